// Round 9
// baseline (329.156 us; speedup 1.0000x reference)
//
#include <hip/hip_runtime.h>
#include <math.h>

// B=16, C=128, H=W=96, HW=9216
#define HW 9216
#define BSTRIDE_QKV  ((size_t)3538944)   // 384*9216 (elements) - q,k,v only
#define BSTRIDE_C    ((size_t)1179648)   // 128*9216 (elements)
#define KVS 24                           // kv partial splits (384 px each)

typedef __attribute__((ext_vector_type(4))) short short4v;
typedef __attribute__((ext_vector_type(8))) short short8v;
typedef __attribute__((ext_vector_type(4))) float f32x4;
typedef __attribute__((ext_vector_type(4))) unsigned short u16x4;

__device__ __forceinline__ unsigned short f2b(float f) {
  union { float f; unsigned u; } v; v.f = f;
  unsigned r = (v.u + 0x7fffu + ((v.u >> 16) & 1u)) >> 16;
  return (unsigned short)r;
}
__device__ __forceinline__ float b2f(unsigned short h) {
  union { unsigned u; float f; } v; v.u = ((unsigned)h) << 16;
  return v.f;
}
// XCD-aware swizzle (nx multiple of 8)
__device__ __forceinline__ int xswz(int x, int nx) {
  return (x & 7) * (nx >> 3) + (x >> 3);
}

// ---------------- f32 -> bf16 weight conversion ----------------
__global__ void cvt_kernel(const float* __restrict__ in, unsigned short* __restrict__ out, int n) {
  int i = blockIdx.x * 256 + threadIdx.x;
  if (i < n) out[i] = f2b(in[i]);
}

// ---------------- GEMM, K=128, swapped-operand: D[px][oc] per lane = 4 consecutive px.
// A-frags = activation tile from LDS Bt[px][k]. B-frags = weights [oc][128] k-contig.
template<int BSRC_F32, int OUT_F32, int NOCB>
__global__ __launch_bounds__(256) void gemm_k128s(
    const unsigned short* __restrict__ A, const void* __restrict__ Bv,
    const float* __restrict__ bias, void* __restrict__ Ov,
    size_t bstrB, size_t bstrO)
{
  __shared__ unsigned short Bt[128 * 132];
  const int t = threadIdx.x, lane = t & 63, wave = t >> 6;
  const int wr = wave >> 1, wc = wave & 1;
  const int l4 = lane & 15, lg = lane >> 4;
  const int pb = xswz(blockIdx.x, 72) << 7, b = blockIdx.y;

  if (BSRC_F32) {
    const float* B = (const float*)Bv + (size_t)b * bstrB;
    #pragma unroll
    for (int i = 0; i < 8; ++i) {
      int id = t + (i << 8);
      int kp = id >> 5, pg = id & 31;
      const float* r0 = B + (size_t)(2 * kp) * HW + pb + (pg << 2);
      f32x4 a = *(const f32x4*)r0;
      f32x4 c = *(const f32x4*)(r0 + HW);
      #pragma unroll
      for (int j = 0; j < 4; ++j)
        *(unsigned*)&Bt[((pg << 2) + j) * 132 + 2 * kp] =
            (unsigned)f2b(a[j]) | ((unsigned)f2b(c[j]) << 16);
    }
  } else {
    const unsigned short* B = (const unsigned short*)Bv + (size_t)b * bstrB;
    #pragma unroll
    for (int i = 0; i < 8; ++i) {
      int id = t + (i << 8);
      int kp = id >> 5, pg = id & 31;
      const unsigned short* r0 = B + (size_t)(2 * kp) * HW + pb + (pg << 2);
      u16x4 a = *(const u16x4*)r0;
      u16x4 c = *(const u16x4*)(r0 + HW);
      #pragma unroll
      for (int j = 0; j < 4; ++j)
        *(unsigned*)&Bt[((pg << 2) + j) * 132 + 2 * kp] =
            (unsigned)a[j] | ((unsigned)c[j] << 16);
    }
  }

  __syncthreads();

  short8v af[4][4];
  #pragma unroll
  for (int mp = 0; mp < 4; ++mp)
    #pragma unroll
    for (int ks = 0; ks < 4; ++ks) {
      int base = (wr * 64 + mp * 16 + l4) * 132 + ks * 32 + lg * 8;
      short4v lo = *(const short4v*)&Bt[base];
      short4v hi = *(const short4v*)&Bt[base + 4];
      short8v v;
      v[0] = lo[0]; v[1] = lo[1]; v[2] = lo[2]; v[3] = lo[3];
      v[4] = hi[0]; v[5] = hi[1]; v[6] = hi[2]; v[7] = hi[3];
      af[mp][ks] = v;
    }

  for (int co = 0; co < NOCB; ++co) {
    f32x4 acc[4][4];
    #pragma unroll
    for (int mp = 0; mp < 4; ++mp)
      #pragma unroll
      for (int nd = 0; nd < 4; ++nd) acc[mp][nd] = (f32x4){0.f, 0.f, 0.f, 0.f};

    #pragma unroll
    for (int ks = 0; ks < 4; ++ks) {
      short8v bfk[4];
      #pragma unroll
      for (int nd = 0; nd < 4; ++nd)
        bfk[nd] = *(const short8v*)(A + (size_t)(co * 128 + wc * 64 + nd * 16 + l4) * 128 + ks * 32 + lg * 8);
      #pragma unroll
      for (int nd = 0; nd < 4; ++nd)
        #pragma unroll
        for (int mp = 0; mp < 4; ++mp)
          acc[mp][nd] = __builtin_amdgcn_mfma_f32_16x16x32_bf16(af[mp][ks], bfk[nd], acc[mp][nd], 0, 0, 0);
    }

    float bb[4];
    #pragma unroll
    for (int nd = 0; nd < 4; ++nd) bb[nd] = bias[co * 128 + wc * 64 + nd * 16 + l4];

    if (OUT_F32) {
      float* O = (float*)Ov + (size_t)b * bstrO;
      #pragma unroll
      for (int mp = 0; mp < 4; ++mp) {
        int px = pb + wr * 64 + mp * 16 + lg * 4;
        #pragma unroll
        for (int nd = 0; nd < 4; ++nd) {
          int oc = co * 128 + wc * 64 + nd * 16 + l4;
          f32x4 v;
          #pragma unroll
          for (int i = 0; i < 4; ++i) v[i] = acc[mp][nd][i] + bb[nd];
          *(f32x4*)&O[(size_t)oc * HW + px] = v;
        }
      }
    } else {
      unsigned short* O = (unsigned short*)Ov + (size_t)b * bstrO;
      #pragma unroll
      for (int mp = 0; mp < 4; ++mp) {
        int px = pb + wr * 64 + mp * 16 + lg * 4;
        #pragma unroll
        for (int nd = 0; nd < 4; ++nd) {
          int oc = co * 128 + wc * 64 + nd * 16 + l4;
          u16x4 v;
          #pragma unroll
          for (int i = 0; i < 4; ++i) v[i] = f2b(acc[mp][nd][i] + bb[nd]);
          *(u16x4*)&O[(size_t)oc * HW + px] = v;
        }
      }
    }
  }
}

// ---------------- depthwise convs, strip-vectorized ----------------
__device__ __forceinline__ void stage_plane(const unsigned short* __restrict__ g,
                                            float* __restrict__ sp, int t) {
  #pragma unroll
  for (int i = 0; i < 9; ++i) {
    int f = (t + (i << 8)) << 2;
    u16x4 u = *(const u16x4*)&g[f];
    f32x4 fv;
    fv[0] = b2f(u[0]); fv[1] = b2f(u[1]); fv[2] = b2f(u[2]); fv[3] = b2f(u[3]);
    *(f32x4*)&sp[f] = fv;
  }
}

__device__ __forceinline__ f32x4 conv3_strip(const float* __restrict__ sp, int base,
                                             const float* __restrict__ w9,
                                             bool j0, bool j23, f32x4* cen) {
  f32x4 acc = (f32x4){0.f, 0.f, 0.f, 0.f};
  #pragma unroll
  for (int ky = 0; ky < 3; ++ky) {
    const float* rowp = sp + base + (ky - 1) * 96;
    f32x4 w0 = *(const f32x4*)(rowp - 4);
    f32x4 w1 = *(const f32x4*)(rowp);
    f32x4 w2 = *(const f32x4*)(rowp + 4);
    float xm1 = j0 ? 0.f : w0[3];
    float xp4 = j23 ? 0.f : w2[0];
    float k0 = w9[ky * 3], k1 = w9[ky * 3 + 1], k2 = w9[ky * 3 + 2];
    acc[0] += k0 * xm1   + k1 * w1[0] + k2 * w1[1];
    acc[1] += k0 * w1[0] + k1 * w1[1] + k2 * w1[2];
    acc[2] += k0 * w1[1] + k1 * w1[2] + k2 * w1[3];
    acc[3] += k0 * w1[2] + k1 * w1[3] + k2 * xp4;
    if (ky == 1) *cen = w1;
  }
  return acc;
}

__global__ __launch_bounds__(256) void dwconv_kernel(
    unsigned short* __restrict__ qkvo,
    const float* __restrict__ w_q, const float* __restrict__ b_q,
    const float* __restrict__ w_k, const float* __restrict__ b_k,
    const float* __restrict__ w_v, const float* __restrict__ b_v,
    const float* __restrict__ w_lepe, const float* __restrict__ b_lepe,
    unsigned short* __restrict__ lp, float* __restrict__ ksum)
{
  __shared__ float sb[9612];
  __shared__ float red[256];
  const int c = blockIdx.x, b = blockIdx.y, t = threadIdx.x;
  unsigned short* qg = qkvo + ((size_t)b * 384 + c) * HW;
  unsigned short* kg = qg + (size_t)128 * HW;
  unsigned short* vg = qg + (size_t)256 * HW;
  unsigned short* lg = lp + ((size_t)b * 128 + c) * HW;
  float* sp = sb + 196;

  for (int i = t; i < 384; i += 256) {
    int idx = (i < 192) ? (i - 192) : (9024 + i);
    sp[idx] = 0.f;
  }

  // ---- Q ----
  {
    stage_plane(qg, sp, t);
    float w9[9];
    #pragma unroll
    for (int i = 0; i < 9; ++i) w9[i] = w_q[c * 9 + i];
    float bb = b_q[c];
    __syncthreads();
    for (int i = 0; i < 9; ++i) {
      int s = t + (i << 8);
      int r = s / 24, j = s - r * 24;
      int base = r * 96 + (j << 2);
      f32x4 cen;
      f32x4 a = conv3_strip(sp, base, w9, j == 0, j == 23, &cen);
      u16x4 o;
      #pragma unroll
      for (int k = 0; k < 4; ++k) {
        float v = cen[k] + bb + a[k];
        o[k] = f2b(v > 0.f ? v + 1.f : __expf(v));
      }
      *(u16x4*)&qg[base] = o;
    }
    __syncthreads();
  }
  // ---- K ----
  float kacc = 0.f;
  {
    stage_plane(kg, sp, t);
    float w9[9];
    #pragma unroll
    for (int i = 0; i < 9; ++i) w9[i] = w_k[c * 9 + i];
    float bb = b_k[c];
    __syncthreads();
    for (int i = 0; i < 9; ++i) {
      int s = t + (i << 8);
      int r = s / 24, j = s - r * 24;
      int base = r * 96 + (j << 2);
      f32x4 cen;
      f32x4 a = conv3_strip(sp, base, w9, j == 0, j == 23, &cen);
      u16x4 o;
      #pragma unroll
      for (int k = 0; k < 4; ++k) {
        float v = cen[k] + bb + a[k];
        float e = v > 0.f ? v + 1.f : __expf(v);
        o[k] = f2b(e);
        kacc += e;
      }
      *(u16x4*)&kg[base] = o;
    }
    __syncthreads();
  }
  // ---- V + lepe (lepe stored bf16) ----
  {
    stage_plane(vg, sp, t);
    float w9[9], w25[25];
    #pragma unroll
    for (int i = 0; i < 9; ++i) w9[i] = w_v[c * 9 + i];
    #pragma unroll
    for (int i = 0; i < 25; ++i) w25[i] = w_lepe[c * 25 + i];
    float bv = b_v[c], bl = b_lepe[c];
    __syncthreads();
    for (int i = 0; i < 9; ++i) {
      int s = t + (i << 8);
      int r = s / 24, j = s - r * 24;
      int base = r * 96 + (j << 2);
      bool j0 = (j == 0), j23 = (j == 23);
      f32x4 a3 = (f32x4){0.f, 0.f, 0.f, 0.f};
      f32x4 a5 = (f32x4){0.f, 0.f, 0.f, 0.f};
      f32x4 cen = (f32x4){0.f, 0.f, 0.f, 0.f};
      #pragma unroll
      for (int ky = 0; ky < 5; ++ky) {
        const float* rowp = sp + base + (ky - 2) * 96;
        f32x4 w0 = *(const f32x4*)(rowp - 4);
        f32x4 w1 = *(const f32x4*)(rowp);
        f32x4 w2 = *(const f32x4*)(rowp + 4);
        float xm2 = j0 ? 0.f : w0[2];
        float xm1 = j0 ? 0.f : w0[3];
        float xp4 = j23 ? 0.f : w2[0];
        float xp5 = j23 ? 0.f : w2[1];
        const float* wr5 = w25 + ky * 5;
        a5[0] += wr5[0]*xm2   + wr5[1]*xm1   + wr5[2]*w1[0] + wr5[3]*w1[1] + wr5[4]*w1[2];
        a5[1] += wr5[0]*xm1   + wr5[1]*w1[0] + wr5[2]*w1[1] + wr5[3]*w1[2] + wr5[4]*w1[3];
        a5[2] += wr5[0]*w1[0] + wr5[1]*w1[1] + wr5[2]*w1[2] + wr5[3]*w1[3] + wr5[4]*xp4;
        a5[3] += wr5[0]*w1[1] + wr5[1]*w1[2] + wr5[2]*w1[3] + wr5[3]*xp4   + wr5[4]*xp5;
        if (ky >= 1 && ky <= 3) {
          float k0 = w9[(ky-1)*3], k1 = w9[(ky-1)*3+1], k2 = w9[(ky-1)*3+2];
          a3[0] += k0 * xm1   + k1 * w1[0] + k2 * w1[1];
          a3[1] += k0 * w1[0] + k1 * w1[1] + k2 * w1[2];
          a3[2] += k0 * w1[1] + k1 * w1[2] + k2 * w1[3];
          a3[3] += k0 * w1[2] + k1 * w1[3] + k2 * xp4;
          if (ky == 2) cen = w1;
        }
      }
      u16x4 o, lo16;
      #pragma unroll
      for (int k = 0; k < 4; ++k) {
        o[k] = f2b(cen[k] + bv + a3[k]);
        lo16[k] = f2b(bl + a5[k]);
      }
      *(u16x4*)&vg[base] = o;
      *(u16x4*)&lg[base] = lo16;
    }
  }
  red[t] = kacc; __syncthreads();
  for (int s2 = 128; s2 > 0; s2 >>= 1) { if (t < s2) red[t] += red[t + s2]; __syncthreads(); }
  if (t == 0) ksum[b * 128 + c] = red[0];
}

// ---------------- kv partials over 384-px splits + fused vmean ----------------
__global__ __launch_bounds__(256) void kv_mfma(
    const unsigned short* __restrict__ qkvo, float* __restrict__ part,
    float* __restrict__ vmean)
{
  __shared__ float vml[2][384];
  const int t = threadIdx.x, lane = t & 63, wave = t >> 6;
  const int wr = wave >> 1, wc = wave & 1;
  const int l4 = lane & 15, lg = lane >> 4;
  const int s = xswz(blockIdx.x, KVS), b = blockIdx.y;
  const unsigned short* kbase = qkvo + (size_t)b * BSTRIDE_QKV + (size_t)128 * HW;
  const unsigned short* vbase = kbase + (size_t)128 * HW;
  const int p0 = s * 384;

  f32x4 acc[4][4];
  #pragma unroll
  for (int m = 0; m < 4; ++m)
    #pragma unroll
    for (int n = 0; n < 4; ++n) acc[m][n] = (f32x4){0.f, 0.f, 0.f, 0.f};

  for (int kk = 0; kk < 12; ++kk) {
    int p = p0 + kk * 32 + lg * 8;
    short8v ka[4], va[4];
    #pragma unroll
    for (int m = 0; m < 4; ++m) ka[m] = *(const short8v*)(kbase + (size_t)(wr * 64 + m * 16 + l4) * HW + p);
    #pragma unroll
    for (int n = 0; n < 4; ++n) va[n] = *(const short8v*)(vbase + (size_t)(wc * 64 + n * 16 + l4) * HW + p);

    if (wr == 0) {
      float pv[8];
      #pragma unroll
      for (int e = 0; e < 8; ++e) {
        pv[e] = b2f((unsigned short)va[0][e]) + b2f((unsigned short)va[1][e])
              + b2f((unsigned short)va[2][e]) + b2f((unsigned short)va[3][e]);
        #pragma unroll
        for (int m2 = 1; m2 < 16; m2 <<= 1)
          pv[e] += __shfl_xor(pv[e], m2, 64);
      }
      if (l4 == 0) {
        #pragma unroll
        for (int e = 0; e < 8; ++e) vml[wc][kk * 32 + lg * 8 + e] = pv[e];
      }
    }

    #pragma unroll
    for (int n = 0; n < 4; ++n)
      #pragma unroll
      for (int m = 0; m < 4; ++m)
        acc[m][n] = __builtin_amdgcn_mfma_f32_16x16x32_bf16(ka[m], va[n], acc[m][n], 0, 0, 0);
  }

  float* pp = part + ((size_t)b * KVS + s) * 16384;
  #pragma unroll
  for (int m = 0; m < 4; ++m)
    #pragma unroll
    for (int n = 0; n < 4; ++n) {
      int d = wc * 64 + n * 16 + l4;
      #pragma unroll
      for (int i = 0; i < 4; ++i) {
        int cch = wr * 64 + m * 16 + lg * 4 + i;
        pp[(cch << 7) + d] = acc[m][n][i];
      }
    }

  __syncthreads();
  for (int i = t; i < 384; i += 256)
    vmean[(size_t)b * HW + p0 + i] = (vml[0][i] + vml[1][i]) * (1.f / 128.f);
}

// ---------------- reduce partials over KVS splits -> kvT[d][c] bf16 ----------------
__global__ void kvreduce(const float* __restrict__ part, unsigned short* __restrict__ kvT) {
  const int b = blockIdx.y;
  const int e0 = blockIdx.x * 2048 + threadIdx.x;
  const float* pb_ = part + (size_t)b * KVS * 16384;
  for (int i = 0; i < 8; ++i) {
    int e = e0 + i * 256;
    int cch = e >> 7, d = e & 127;
    float sum = 0.f;
    #pragma unroll 8
    for (int s = 0; s < KVS; ++s) sum += pb_[(size_t)s * 16384 + e];
    kvT[(size_t)b * 16384 + d * 128 + cch] = f2b(sum);
  }
}

// ---------------- fused o-GEMM + attention + projection ----------------
// Phase 0: stage x-tile -> Bt, MFMA_o: o[px][d] = x @ w_o^T (held in regs).
// Phase 1: stage q' -> Bt, MFMA1: acc = q' @ kvT with fused parallel z-partials.
// Phase 2: epilogue T = (acc*zf - z*vmean + lepe)*(o+b_o) -> Tt (LDS).
// Phase 3: MFMA2: out = T @ w_proj^T + b_proj, nontemporal f32x4 stores.
__global__ __launch_bounds__(256) void attn_proj(
    const unsigned short* __restrict__ qkvo, const float* __restrict__ xin,
    const unsigned short* __restrict__ kvT,
    const float* __restrict__ ksum, const float* __restrict__ vmean,
    const unsigned short* __restrict__ lp,
    const unsigned short* __restrict__ woh, const float* __restrict__ b_o,
    const unsigned short* __restrict__ wph, const float* __restrict__ b_proj,
    float* __restrict__ outp)
{
  __shared__ unsigned short Bt[128 * 132];
  __shared__ float zb[128];
  __shared__ float km[128];
  const int t = threadIdx.x, lane = t & 63, wave = t >> 6;
  const int wr = wave >> 1, wc = wave & 1;
  const int l4 = lane & 15, lg = lane >> 4;
  const int pb = xswz(blockIdx.x, 72) << 7, b = blockIdx.y;
  const float kSCf = (float)(0.08838834764831843 / 9216.0);

  const unsigned short* qs = qkvo + (size_t)b * BSTRIDE_QKV;     // q' section
  const unsigned short* lpb = lp + (size_t)b * BSTRIDE_C;        // lepe bf16
  float* ob = outp + (size_t)b * BSTRIDE_C;                      // final out f32

  if (t < 128) km[t] = ksum[(b << 7) + t];

  // ---- Phase 0: stage x tile transposed -> Bt[px][ic] (bf16) ----
  {
    const float* B = xin + (size_t)b * BSTRIDE_C;
    #pragma unroll
    for (int i = 0; i < 8; ++i) {
      int id = t + (i << 8);
      int kp = id >> 5, pg = id & 31;
      const float* r0 = B + (size_t)(2 * kp) * HW + pb + (pg << 2);
      f32x4 a = *(const f32x4*)r0;
      f32x4 c = *(const f32x4*)(r0 + HW);
      #pragma unroll
      for (int j = 0; j < 4; ++j)
        *(unsigned*)&Bt[((pg << 2) + j) * 132 + 2 * kp] =
            (unsigned)f2b(a[j]) | ((unsigned)f2b(c[j]) << 16);
    }
  }
  __syncthreads();   // covers km write too

  // o-GEMM: A = x frags (px rows), B = w_o frags (d rows, k-contig)
  f32x4 acco[4][4];
  #pragma unroll
  for (int mp = 0; mp < 4; ++mp)
    #pragma unroll
    for (int nd = 0; nd < 4; ++nd) acco[mp][nd] = (f32x4){0.f, 0.f, 0.f, 0.f};

  #pragma unroll
  for (int ks = 0; ks < 4; ++ks) {
    short8v ax[4];
    #pragma unroll
    for (int mp = 0; mp < 4; ++mp) {
      int base = (wr * 64 + mp * 16 + l4) * 132 + ks * 32 + lg * 8;
      short4v lo = *(const short4v*)&Bt[base];
      short4v hi = *(const short4v*)&Bt[base + 4];
      short8v v;
      v[0] = lo[0]; v[1] = lo[1]; v[2] = lo[2]; v[3] = lo[3];
      v[4] = hi[0]; v[5] = hi[1]; v[6] = hi[2]; v[7] = hi[3];
      ax[mp] = v;
    }
    short8v pw[4];
    #pragma unroll
    for (int nd = 0; nd < 4; ++nd)
      pw[nd] = *(const short8v*)(woh + (size_t)(wc * 64 + nd * 16 + l4) * 128 + ks * 32 + lg * 8);
    #pragma unroll
    for (int nd = 0; nd < 4; ++nd)
      #pragma unroll
      for (int mp = 0; mp < 4; ++mp)
        acco[mp][nd] = __builtin_amdgcn_mfma_f32_16x16x32_bf16(ax[mp], pw[nd], acco[mp][nd], 0, 0, 0);
  }

  __syncthreads();   // all Bt (x) reads done

  // ---- Phase 1: stage q' -> Bt ----
  #pragma unroll
  for (int i = 0; i < 8; ++i) {
    int id = t + (i << 8);
    int kp = id >> 5, pg = id & 31;
    const unsigned short* r0 = qs + (size_t)(2 * kp) * HW + pb + (pg << 2);
    u16x4 a = *(const u16x4*)r0;
    u16x4 c = *(const u16x4*)(r0 + HW);
    #pragma unroll
    for (int j = 0; j < 4; ++j)
      *(unsigned*)&Bt[((pg << 2) + j) * 132 + 2 * kp] =
          (unsigned)a[j] | ((unsigned)c[j] << 16);
  }

  f32x4 acc[4][4];
  #pragma unroll
  for (int mp = 0; mp < 4; ++mp)
    #pragma unroll
    for (int nd = 0; nd < 4; ++nd) acc[mp][nd] = (f32x4){0.f, 0.f, 0.f, 0.f};

  __syncthreads();

  // MFMA1 with fused parallel z-partials: zp4[mp] accumulates
  // sum_c q'[c][px=wr*64+mp*16+l4] * ksum[c] over this lane's c-slice.
  const unsigned short* Ab = kvT + (size_t)b * 16384;
  float zp4[4] = {0.f, 0.f, 0.f, 0.f};
  #pragma unroll
  for (int ks = 0; ks < 4; ++ks) {
    f32x4 km0 = *(const f32x4*)&km[ks * 32 + lg * 8];
    f32x4 km1 = *(const f32x4*)&km[ks * 32 + lg * 8 + 4];
    short8v aq[4];
    #pragma unroll
    for (int mp = 0; mp < 4; ++mp) {
      int base = (wr * 64 + mp * 16 + l4) * 132 + ks * 32 + lg * 8;
      short4v lo = *(const short4v*)&Bt[base];
      short4v hi = *(const short4v*)&Bt[base + 4];
      short8v v;
      v[0] = lo[0]; v[1] = lo[1]; v[2] = lo[2]; v[3] = lo[3];
      v[4] = hi[0]; v[5] = hi[1]; v[6] = hi[2]; v[7] = hi[3];
      aq[mp] = v;
      #pragma unroll
      for (int e = 0; e < 4; ++e)
        zp4[mp] += b2f((unsigned short)v[e]) * km0[e]
                 + b2f((unsigned short)v[e + 4]) * km1[e];
    }
    short8v bkv[4];
    #pragma unroll
    for (int nd = 0; nd < 4; ++nd)
      bkv[nd] = *(const short8v*)(Ab + (size_t)(wc * 64 + nd * 16 + l4) * 128 + ks * 32 + lg * 8);
    #pragma unroll
    for (int nd = 0; nd < 4; ++nd)
      #pragma unroll
      for (int mp = 0; mp < 4; ++mp)
        acc[mp][nd] = __builtin_amdgcn_mfma_f32_16x16x32_bf16(aq[mp], bkv[nd], acc[mp][nd], 0, 0, 0);
  }

  // reduce z over lg (lane bits 4,5); px = wr*64+mp*16+l4
  #pragma unroll
  for (int mp = 0; mp < 4; ++mp) {
    zp4[mp] += __shfl_xor(zp4[mp], 16, 64);
    zp4[mp] += __shfl_xor(zp4[mp], 32, 64);
  }
  if (wc == 0 && lg == 0) {
    #pragma unroll
    for (int mp = 0; mp < 4; ++mp) zb[wr * 64 + mp * 16 + l4] = zp4[mp];
  }

  __syncthreads();   // Bt reads done; zb visible

  // ---- Phase 2: epilogue T -> Tt (reuse Bt) ----
  float bo[4];
  #pragma unroll
  for (int nd = 0; nd < 4; ++nd) bo[nd] = b_o[wc * 64 + nd * 16 + l4];

  #pragma unroll
  for (int mp = 0; mp < 4; ++mp) {
    int pxl = wr * 64 + mp * 16 + lg * 4;
    int px = pb + pxl;
    f32x4 zv = *(const f32x4*)&zb[pxl];
    f32x4 vm = *(const f32x4*)&vmean[(size_t)b * HW + px];
    f32x4 zfv, zvmv;
    #pragma unroll
    for (int i = 0; i < 4; ++i) {
      float z = zv[i] * kSCf;
      zfv[i]  = kSCf * (1.f + 1.f / (z + 1e-6f));
      zvmv[i] = z * vm[i];
    }
    #pragma unroll
    for (int nd = 0; nd < 4; ++nd) {
      int d = wc * 64 + nd * 16 + l4;
      u16x4 lev = *(const u16x4*)&lpb[(size_t)d * HW + px];
      #pragma unroll
      for (int i = 0; i < 4; ++i) {
        float ov = acco[mp][nd][i] + bo[nd];
        float r = (acc[mp][nd][i] * zfv[i] - zvmv[i] + b2f(lev[i])) * ov;
        Bt[(pxl + i) * 132 + d] = f2b(r);
      }
    }
  }

  __syncthreads();   // Tt complete

  // ---- Phase 3: MFMA2 out = T @ w_proj^T ----
  f32x4 acc2[4][4];
  #pragma unroll
  for (int mp = 0; mp < 4; ++mp)
    #pragma unroll
    for (int nd = 0; nd < 4; ++nd) acc2[mp][nd] = (f32x4){0.f, 0.f, 0.f, 0.f};

  #pragma unroll
  for (int ks = 0; ks < 4; ++ks) {
    short8v aq[4];
    #pragma unroll
    for (int mp = 0; mp < 4; ++mp) {
      int base = (wr * 64 + mp * 16 + l4) * 132 + ks * 32 + lg * 8;
      short4v lo = *(const short4v*)&Bt[base];
      short4v hi = *(const short4v*)&Bt[base + 4];
      short8v v;
      v[0] = lo[0]; v[1] = lo[1]; v[2] = lo[2]; v[3] = lo[3];
      v[4] = hi[0]; v[5] = hi[1]; v[6] = hi[2]; v[7] = hi[3];
      aq[mp] = v;
    }
    short8v pw[4];
    #pragma unroll
    for (int nd = 0; nd < 4; ++nd)
      pw[nd] = *(const short8v*)(wph + (size_t)(wc * 64 + nd * 16 + l4) * 128 + ks * 32 + lg * 8);
    #pragma unroll
    for (int nd = 0; nd < 4; ++nd)
      #pragma unroll
      for (int mp = 0; mp < 4; ++mp)
        acc2[mp][nd] = __builtin_amdgcn_mfma_f32_16x16x32_bf16(aq[mp], pw[nd], acc2[mp][nd], 0, 0, 0);
  }

  float bb[4];
  #pragma unroll
  for (int nd = 0; nd < 4; ++nd) bb[nd] = b_proj[wc * 64 + nd * 16 + l4];

  #pragma unroll
  for (int mp = 0; mp < 4; ++mp) {
    int px = pb + wr * 64 + mp * 16 + lg * 4;
    #pragma unroll
    for (int nd = 0; nd < 4; ++nd) {
      int oc = wc * 64 + nd * 16 + l4;
      f32x4 v;
      #pragma unroll
      for (int i = 0; i < 4; ++i) v[i] = acc2[mp][nd][i] + bb[nd];
      __builtin_nontemporal_store(v, (f32x4*)&ob[(size_t)oc * HW + px]);
    }
  }
}

extern "C" void kernel_launch(void* const* d_in, const int* in_sizes, int n_in,
                              void* d_out, int out_size, void* d_ws, size_t ws_size,
                              hipStream_t stream) {
  const float* x      = (const float*)d_in[0];
  const float* w_qkvo = (const float*)d_in[3];
  const float* b_qkvo = (const float*)d_in[4];
  const float* w_lepe = (const float*)d_in[5];
  const float* b_lepe = (const float*)d_in[6];
  const float* w_proj = (const float*)d_in[7];
  const float* b_proj = (const float*)d_in[8];
  const float* w_q = (const float*)d_in[9];
  const float* b_q = (const float*)d_in[10];
  const float* w_k = (const float*)d_in[11];
  const float* b_k = (const float*)d_in[12];
  const float* w_v = (const float*)d_in[13];
  const float* b_v = (const float*)d_in[14];
  float* out = (float*)d_out;

  // global: bf16 weights (all 512 rows of w_qkvo; rows 384.. = w_o used in attn_proj)
  unsigned short* wqh = (unsigned short*)d_ws;   // 65536
  unsigned short* wph = wqh + 65536;             // 16384  -> 163840 bytes total
  // per-batch (bytes): qkv bf16 7,077,888 ; kvpart f32 1,572,864 ; kvT bf16 32,768 ;
  //                    ksum f32 512 ; vmean f32 36,864 ; lepe bf16 2,359,296
  const size_t perb_bytes = 7077888 + 1572864 + 32768 + 512 + 36864 + 2359296;
  // Cap G at 8: per-pass working set (~165 MB incl. x/out slices) fits the
  // 256 MiB Infinity Cache, so intermediates stay L3-resident between kernels.
  int G = 0;
  for (int g = 8; g >= 1; g >>= 1)
    if ((size_t)163840 + (size_t)g * perb_bytes <= ws_size) { G = g; break; }
  if (G == 0) return;

  size_t off = 163840;
  unsigned short* qkv_h = (unsigned short*)((char*)d_ws + off);  off += (size_t)G * 7077888;
  float* kvpart = (float*)((char*)d_ws + off);                   off += (size_t)G * 1572864;
  unsigned short* kvT = (unsigned short*)((char*)d_ws + off);    off += (size_t)G * 32768;
  float* ksum = (float*)((char*)d_ws + off);                     off += (size_t)G * 512;
  float* vmeanp = (float*)((char*)d_ws + off);                   off += (size_t)G * 36864;
  unsigned short* lepe_h = (unsigned short*)((char*)d_ws + off);

  cvt_kernel<<<dim3(256), 256, 0, stream>>>(w_qkvo, wqh, 65536);
  cvt_kernel<<<dim3(64),  256, 0, stream>>>(w_proj, wph, 16384);

  for (int b0 = 0; b0 < 16; b0 += G) {
    const float* xc  = x   + (size_t)b0 * BSTRIDE_C;
    float*       oc_ = out + (size_t)b0 * BSTRIDE_C;

    // qkv = 1x1 conv (bf16 out, channel-major); 3 oc-blocks (q,k,v) per px-tile
    gemm_k128s<1, 0, 3><<<dim3(72, G), 256, 0, stream>>>(
        wqh, xc, b_qkvo, qkv_h, BSTRIDE_C, BSTRIDE_QKV);
    // depthwise 3x3 q,k,v (in place, elu+1 on q,k), 5x5 lepe (bf16) -> ws, ksum
    dwconv_kernel<<<dim3(128, G), 256, 0, stream>>>(qkv_h, w_q, b_q, w_k, b_k, w_v, b_v,
                                                    w_lepe, b_lepe, lepe_h, ksum);
    // kv partials (+fused vmean) + reduce (-> kvT bf16)
    kv_mfma<<<dim3(KVS, G), 256, 0, stream>>>(qkv_h, kvpart, vmeanp);
    kvreduce<<<dim3(8, G), 256, 0, stream>>>(kvpart, kvT);
    // fused o-GEMM + attention epilogue + projection -> d_out slice (f32, nt)
    attn_proj<<<dim3(72, G), 256, 0, stream>>>(qkv_h, xc, kvT, ksum, vmeanp, lepe_h,
                                               wqh + (size_t)384 * 128, b_qkvo + 384,
                                               wph, b_proj, oc_);
  }
}

// Round 10
// 278.275 us; speedup vs baseline: 1.1828x; 1.1828x over previous
//
#include <hip/hip_runtime.h>
#include <math.h>

// B=16, C=128, H=W=96, HW=9216
#define HW 9216
#define BSTRIDE_QKV  ((size_t)3538944)   // 384*9216 (elements) - q,k,v only
#define BSTRIDE_C    ((size_t)1179648)   // 128*9216 (elements)
#define KVS 24                           // kv partial splits (384 px each)

typedef __attribute__((ext_vector_type(4))) short short4v;
typedef __attribute__((ext_vector_type(8))) short short8v;
typedef __attribute__((ext_vector_type(4))) float f32x4;
typedef __attribute__((ext_vector_type(4))) unsigned short u16x4;

__device__ __forceinline__ unsigned short f2b(float f) {
  union { float f; unsigned u; } v; v.f = f;
  unsigned r = (v.u + 0x7fffu + ((v.u >> 16) & 1u)) >> 16;
  return (unsigned short)r;
}
__device__ __forceinline__ float b2f(unsigned short h) {
  union { unsigned u; float f; } v; v.u = ((unsigned)h) << 16;
  return v.f;
}
// XCD-aware swizzle (nx multiple of 8)
__device__ __forceinline__ int xswz(int x, int nx) {
  return (x & 7) * (nx >> 3) + (x >> 3);
}

// ---------------- f32 -> bf16 weight conversion ----------------
__global__ void cvt_kernel(const float* __restrict__ in, unsigned short* __restrict__ out, int n) {
  int i = blockIdx.x * 256 + threadIdx.x;
  if (i < n) out[i] = f2b(in[i]);
}

// vectorized f32 -> bf16, 8 elements/thread
__global__ void cvt8_kernel(const float* __restrict__ in, unsigned short* __restrict__ out, int n8) {
  int i = blockIdx.x * 256 + threadIdx.x;
  if (i < n8) {
    f32x4 a = ((const f32x4*)in)[2 * i];
    f32x4 c = ((const f32x4*)in)[2 * i + 1];
    u16x4 o1, o2;
    #pragma unroll
    for (int j = 0; j < 4; ++j) { o1[j] = f2b(a[j]); o2[j] = f2b(c[j]); }
    ((u16x4*)out)[2 * i] = o1;
    ((u16x4*)out)[2 * i + 1] = o2;
  }
}

// ---------------- GEMM, K=128, swapped-operand: D[px][oc] per lane = 4 consecutive px.
// A-frags = activation tile from LDS Bt[px][k]. B-frags = weights [oc][128] k-contig.
template<int BSRC_F32, int OUT_F32, int NOCB>
__global__ __launch_bounds__(256) void gemm_k128s(
    const unsigned short* __restrict__ A, const void* __restrict__ Bv,
    const float* __restrict__ bias, void* __restrict__ Ov,
    size_t bstrB, size_t bstrO)
{
  __shared__ unsigned short Bt[128 * 132];
  const int t = threadIdx.x, lane = t & 63, wave = t >> 6;
  const int wr = wave >> 1, wc = wave & 1;
  const int l4 = lane & 15, lg = lane >> 4;
  const int pb = xswz(blockIdx.x, 72) << 7, b = blockIdx.y;

  if (BSRC_F32) {
    const float* B = (const float*)Bv + (size_t)b * bstrB;
    #pragma unroll
    for (int i = 0; i < 8; ++i) {
      int id = t + (i << 8);
      int kp = id >> 5, pg = id & 31;
      const float* r0 = B + (size_t)(2 * kp) * HW + pb + (pg << 2);
      f32x4 a = *(const f32x4*)r0;
      f32x4 c = *(const f32x4*)(r0 + HW);
      #pragma unroll
      for (int j = 0; j < 4; ++j)
        *(unsigned*)&Bt[((pg << 2) + j) * 132 + 2 * kp] =
            (unsigned)f2b(a[j]) | ((unsigned)f2b(c[j]) << 16);
    }
  } else {
    const unsigned short* B = (const unsigned short*)Bv + (size_t)b * bstrB;
    #pragma unroll
    for (int i = 0; i < 8; ++i) {
      int id = t + (i << 8);
      int kp = id >> 5, pg = id & 31;
      const unsigned short* r0 = B + (size_t)(2 * kp) * HW + pb + (pg << 2);
      u16x4 a = *(const u16x4*)r0;
      u16x4 c = *(const u16x4*)(r0 + HW);
      #pragma unroll
      for (int j = 0; j < 4; ++j)
        *(unsigned*)&Bt[((pg << 2) + j) * 132 + 2 * kp] =
            (unsigned)a[j] | ((unsigned)c[j] << 16);
    }
  }

  __syncthreads();

  short8v af[4][4];
  #pragma unroll
  for (int mp = 0; mp < 4; ++mp)
    #pragma unroll
    for (int ks = 0; ks < 4; ++ks) {
      int base = (wr * 64 + mp * 16 + l4) * 132 + ks * 32 + lg * 8;
      short4v lo = *(const short4v*)&Bt[base];
      short4v hi = *(const short4v*)&Bt[base + 4];
      short8v v;
      v[0] = lo[0]; v[1] = lo[1]; v[2] = lo[2]; v[3] = lo[3];
      v[4] = hi[0]; v[5] = hi[1]; v[6] = hi[2]; v[7] = hi[3];
      af[mp][ks] = v;
    }

  for (int co = 0; co < NOCB; ++co) {
    f32x4 acc[4][4];
    #pragma unroll
    for (int mp = 0; mp < 4; ++mp)
      #pragma unroll
      for (int nd = 0; nd < 4; ++nd) acc[mp][nd] = (f32x4){0.f, 0.f, 0.f, 0.f};

    #pragma unroll
    for (int ks = 0; ks < 4; ++ks) {
      short8v bfk[4];
      #pragma unroll
      for (int nd = 0; nd < 4; ++nd)
        bfk[nd] = *(const short8v*)(A + (size_t)(co * 128 + wc * 64 + nd * 16 + l4) * 128 + ks * 32 + lg * 8);
      #pragma unroll
      for (int nd = 0; nd < 4; ++nd)
        #pragma unroll
        for (int mp = 0; mp < 4; ++mp)
          acc[mp][nd] = __builtin_amdgcn_mfma_f32_16x16x32_bf16(af[mp][ks], bfk[nd], acc[mp][nd], 0, 0, 0);
    }

    float bb[4];
    #pragma unroll
    for (int nd = 0; nd < 4; ++nd) bb[nd] = bias[co * 128 + wc * 64 + nd * 16 + l4];

    if (OUT_F32) {
      float* O = (float*)Ov + (size_t)b * bstrO;
      #pragma unroll
      for (int mp = 0; mp < 4; ++mp) {
        int px = pb + wr * 64 + mp * 16 + lg * 4;
        #pragma unroll
        for (int nd = 0; nd < 4; ++nd) {
          int oc = co * 128 + wc * 64 + nd * 16 + l4;
          f32x4 v;
          #pragma unroll
          for (int i = 0; i < 4; ++i) v[i] = acc[mp][nd][i] + bb[nd];
          *(f32x4*)&O[(size_t)oc * HW + px] = v;
        }
      }
    } else {
      unsigned short* O = (unsigned short*)Ov + (size_t)b * bstrO;
      #pragma unroll
      for (int mp = 0; mp < 4; ++mp) {
        int px = pb + wr * 64 + mp * 16 + lg * 4;
        #pragma unroll
        for (int nd = 0; nd < 4; ++nd) {
          int oc = co * 128 + wc * 64 + nd * 16 + l4;
          u16x4 v;
          #pragma unroll
          for (int i = 0; i < 4; ++i) v[i] = f2b(acc[mp][nd][i] + bb[nd]);
          *(u16x4*)&O[(size_t)oc * HW + px] = v;
        }
      }
    }
  }
}

// ---------------- depthwise convs, strip-vectorized ----------------
__device__ __forceinline__ void stage_plane(const unsigned short* __restrict__ g,
                                            float* __restrict__ sp, int t) {
  #pragma unroll
  for (int i = 0; i < 9; ++i) {
    int f = (t + (i << 8)) << 2;
    u16x4 u = *(const u16x4*)&g[f];
    f32x4 fv;
    fv[0] = b2f(u[0]); fv[1] = b2f(u[1]); fv[2] = b2f(u[2]); fv[3] = b2f(u[3]);
    *(f32x4*)&sp[f] = fv;
  }
}

__device__ __forceinline__ f32x4 conv3_strip(const float* __restrict__ sp, int base,
                                             const float* __restrict__ w9,
                                             bool j0, bool j23, f32x4* cen) {
  f32x4 acc = (f32x4){0.f, 0.f, 0.f, 0.f};
  #pragma unroll
  for (int ky = 0; ky < 3; ++ky) {
    const float* rowp = sp + base + (ky - 1) * 96;
    f32x4 w0 = *(const f32x4*)(rowp - 4);
    f32x4 w1 = *(const f32x4*)(rowp);
    f32x4 w2 = *(const f32x4*)(rowp + 4);
    float xm1 = j0 ? 0.f : w0[3];
    float xp4 = j23 ? 0.f : w2[0];
    float k0 = w9[ky * 3], k1 = w9[ky * 3 + 1], k2 = w9[ky * 3 + 2];
    acc[0] += k0 * xm1   + k1 * w1[0] + k2 * w1[1];
    acc[1] += k0 * w1[0] + k1 * w1[1] + k2 * w1[2];
    acc[2] += k0 * w1[1] + k1 * w1[2] + k2 * w1[3];
    acc[3] += k0 * w1[2] + k1 * w1[3] + k2 * xp4;
    if (ky == 1) *cen = w1;
  }
  return acc;
}

__global__ __launch_bounds__(256) void dwconv_kernel(
    unsigned short* __restrict__ qkvo,
    const float* __restrict__ w_q, const float* __restrict__ b_q,
    const float* __restrict__ w_k, const float* __restrict__ b_k,
    const float* __restrict__ w_v, const float* __restrict__ b_v,
    const float* __restrict__ w_lepe, const float* __restrict__ b_lepe,
    unsigned short* __restrict__ lp, float* __restrict__ ksum)
{
  __shared__ float sb[9612];
  __shared__ float red[256];
  const int c = blockIdx.x, b = blockIdx.y, t = threadIdx.x;
  unsigned short* qg = qkvo + ((size_t)b * 384 + c) * HW;
  unsigned short* kg = qg + (size_t)128 * HW;
  unsigned short* vg = qg + (size_t)256 * HW;
  unsigned short* lg = lp + ((size_t)b * 128 + c) * HW;
  float* sp = sb + 196;

  for (int i = t; i < 384; i += 256) {
    int idx = (i < 192) ? (i - 192) : (9024 + i);
    sp[idx] = 0.f;
  }

  // ---- Q ----
  {
    stage_plane(qg, sp, t);
    float w9[9];
    #pragma unroll
    for (int i = 0; i < 9; ++i) w9[i] = w_q[c * 9 + i];
    float bb = b_q[c];
    __syncthreads();
    for (int i = 0; i < 9; ++i) {
      int s = t + (i << 8);
      int r = s / 24, j = s - r * 24;
      int base = r * 96 + (j << 2);
      f32x4 cen;
      f32x4 a = conv3_strip(sp, base, w9, j == 0, j == 23, &cen);
      u16x4 o;
      #pragma unroll
      for (int k = 0; k < 4; ++k) {
        float v = cen[k] + bb + a[k];
        o[k] = f2b(v > 0.f ? v + 1.f : __expf(v));
      }
      *(u16x4*)&qg[base] = o;
    }
    __syncthreads();
  }
  // ---- K ----
  float kacc = 0.f;
  {
    stage_plane(kg, sp, t);
    float w9[9];
    #pragma unroll
    for (int i = 0; i < 9; ++i) w9[i] = w_k[c * 9 + i];
    float bb = b_k[c];
    __syncthreads();
    for (int i = 0; i < 9; ++i) {
      int s = t + (i << 8);
      int r = s / 24, j = s - r * 24;
      int base = r * 96 + (j << 2);
      f32x4 cen;
      f32x4 a = conv3_strip(sp, base, w9, j == 0, j == 23, &cen);
      u16x4 o;
      #pragma unroll
      for (int k = 0; k < 4; ++k) {
        float v = cen[k] + bb + a[k];
        float e = v > 0.f ? v + 1.f : __expf(v);
        o[k] = f2b(e);
        kacc += e;
      }
      *(u16x4*)&kg[base] = o;
    }
    __syncthreads();
  }
  // ---- V + lepe (lepe stored bf16) ----
  {
    stage_plane(vg, sp, t);
    float w9[9], w25[25];
    #pragma unroll
    for (int i = 0; i < 9; ++i) w9[i] = w_v[c * 9 + i];
    #pragma unroll
    for (int i = 0; i < 25; ++i) w25[i] = w_lepe[c * 25 + i];
    float bv = b_v[c], bl = b_lepe[c];
    __syncthreads();
    for (int i = 0; i < 9; ++i) {
      int s = t + (i << 8);
      int r = s / 24, j = s - r * 24;
      int base = r * 96 + (j << 2);
      bool j0 = (j == 0), j23 = (j == 23);
      f32x4 a3 = (f32x4){0.f, 0.f, 0.f, 0.f};
      f32x4 a5 = (f32x4){0.f, 0.f, 0.f, 0.f};
      f32x4 cen = (f32x4){0.f, 0.f, 0.f, 0.f};
      #pragma unroll
      for (int ky = 0; ky < 5; ++ky) {
        const float* rowp = sp + base + (ky - 2) * 96;
        f32x4 w0 = *(const f32x4*)(rowp - 4);
        f32x4 w1 = *(const f32x4*)(rowp);
        f32x4 w2 = *(const f32x4*)(rowp + 4);
        float xm2 = j0 ? 0.f : w0[2];
        float xm1 = j0 ? 0.f : w0[3];
        float xp4 = j23 ? 0.f : w2[0];
        float xp5 = j23 ? 0.f : w2[1];
        const float* wr5 = w25 + ky * 5;
        a5[0] += wr5[0]*xm2   + wr5[1]*xm1   + wr5[2]*w1[0] + wr5[3]*w1[1] + wr5[4]*w1[2];
        a5[1] += wr5[0]*xm1   + wr5[1]*w1[0] + wr5[2]*w1[1] + wr5[3]*w1[2] + wr5[4]*w1[3];
        a5[2] += wr5[0]*w1[0] + wr5[1]*w1[1] + wr5[2]*w1[2] + wr5[3]*w1[3] + wr5[4]*xp4;
        a5[3] += wr5[0]*w1[1] + wr5[1]*w1[2] + wr5[2]*w1[3] + wr5[3]*xp4   + wr5[4]*xp5;
        if (ky >= 1 && ky <= 3) {
          float k0 = w9[(ky-1)*3], k1 = w9[(ky-1)*3+1], k2 = w9[(ky-1)*3+2];
          a3[0] += k0 * xm1   + k1 * w1[0] + k2 * w1[1];
          a3[1] += k0 * w1[0] + k1 * w1[1] + k2 * w1[2];
          a3[2] += k0 * w1[1] + k1 * w1[2] + k2 * w1[3];
          a3[3] += k0 * w1[2] + k1 * w1[3] + k2 * xp4;
          if (ky == 2) cen = w1;
        }
      }
      u16x4 o, lo16;
      #pragma unroll
      for (int k = 0; k < 4; ++k) {
        o[k] = f2b(cen[k] + bv + a3[k]);
        lo16[k] = f2b(bl + a5[k]);
      }
      *(u16x4*)&vg[base] = o;
      *(u16x4*)&lg[base] = lo16;
    }
  }
  red[t] = kacc; __syncthreads();
  for (int s2 = 128; s2 > 0; s2 >>= 1) { if (t < s2) red[t] += red[t + s2]; __syncthreads(); }
  if (t == 0) ksum[b * 128 + c] = red[0];
}

// ---------------- kv partials over 384-px splits + fused vmean ----------------
__global__ __launch_bounds__(256) void kv_mfma(
    const unsigned short* __restrict__ qkvo, float* __restrict__ part,
    float* __restrict__ vmean)
{
  __shared__ float vml[2][384];
  const int t = threadIdx.x, lane = t & 63, wave = t >> 6;
  const int wr = wave >> 1, wc = wave & 1;
  const int l4 = lane & 15, lg = lane >> 4;
  const int s = xswz(blockIdx.x, KVS), b = blockIdx.y;
  const unsigned short* kbase = qkvo + (size_t)b * BSTRIDE_QKV + (size_t)128 * HW;
  const unsigned short* vbase = kbase + (size_t)128 * HW;
  const int p0 = s * 384;

  f32x4 acc[4][4];
  #pragma unroll
  for (int m = 0; m < 4; ++m)
    #pragma unroll
    for (int n = 0; n < 4; ++n) acc[m][n] = (f32x4){0.f, 0.f, 0.f, 0.f};

  for (int kk = 0; kk < 12; ++kk) {
    int p = p0 + kk * 32 + lg * 8;
    short8v ka[4], va[4];
    #pragma unroll
    for (int m = 0; m < 4; ++m) ka[m] = *(const short8v*)(kbase + (size_t)(wr * 64 + m * 16 + l4) * HW + p);
    #pragma unroll
    for (int n = 0; n < 4; ++n) va[n] = *(const short8v*)(vbase + (size_t)(wc * 64 + n * 16 + l4) * HW + p);

    if (wr == 0) {
      float pv[8];
      #pragma unroll
      for (int e = 0; e < 8; ++e) {
        pv[e] = b2f((unsigned short)va[0][e]) + b2f((unsigned short)va[1][e])
              + b2f((unsigned short)va[2][e]) + b2f((unsigned short)va[3][e]);
        #pragma unroll
        for (int m2 = 1; m2 < 16; m2 <<= 1)
          pv[e] += __shfl_xor(pv[e], m2, 64);
      }
      if (l4 == 0) {
        #pragma unroll
        for (int e = 0; e < 8; ++e) vml[wc][kk * 32 + lg * 8 + e] = pv[e];
      }
    }

    #pragma unroll
    for (int n = 0; n < 4; ++n)
      #pragma unroll
      for (int m = 0; m < 4; ++m)
        acc[m][n] = __builtin_amdgcn_mfma_f32_16x16x32_bf16(ka[m], va[n], acc[m][n], 0, 0, 0);
  }

  float* pp = part + ((size_t)b * KVS + s) * 16384;
  #pragma unroll
  for (int m = 0; m < 4; ++m)
    #pragma unroll
    for (int n = 0; n < 4; ++n) {
      int d = wc * 64 + n * 16 + l4;
      #pragma unroll
      for (int i = 0; i < 4; ++i) {
        int cch = wr * 64 + m * 16 + lg * 4 + i;
        pp[(cch << 7) + d] = acc[m][n][i];
      }
    }

  __syncthreads();
  for (int i = t; i < 384; i += 256)
    vmean[(size_t)b * HW + p0 + i] = (vml[0][i] + vml[1][i]) * (1.f / 128.f);
}

// ---------------- reduce partials over KVS splits -> kvT[d][c] bf16 ----------------
__global__ void kvreduce(const float* __restrict__ part, unsigned short* __restrict__ kvT) {
  const int b = blockIdx.y;
  const int e0 = blockIdx.x * 2048 + threadIdx.x;
  const float* pb_ = part + (size_t)b * KVS * 16384;
  for (int i = 0; i < 8; ++i) {
    int e = e0 + i * 256;
    int cch = e >> 7, d = e & 127;
    float sum = 0.f;
    #pragma unroll 8
    for (int s = 0; s < KVS; ++s) sum += pb_[(size_t)s * 16384 + e];
    kvT[(size_t)b * 16384 + d * 128 + cch] = f2b(sum);
  }
}

// ---------------- fused o-GEMM + attention + projection ----------------
// Phase 0: stage xh-tile (bf16) -> Bt, MFMA_o: o[px][d] = x @ w_o^T (held in regs).
// Phase 1: stage q' -> Bt, MFMA1: acc = q' @ kvT with fused parallel z-partials.
// Phase 2: epilogue T = (acc*zf - z*vmean + lepe)*(o+b_o) -> Tt (LDS).
// Phase 3: MFMA2: out = T @ w_proj^T + b_proj, nontemporal f32x4 stores.
__global__ __launch_bounds__(256) void attn_proj(
    const unsigned short* __restrict__ qkvo, const unsigned short* __restrict__ xh,
    const unsigned short* __restrict__ kvT,
    const float* __restrict__ ksum, const float* __restrict__ vmean,
    const unsigned short* __restrict__ lp,
    const unsigned short* __restrict__ woh, const float* __restrict__ b_o,
    const unsigned short* __restrict__ wph, const float* __restrict__ b_proj,
    float* __restrict__ outp)
{
  __shared__ unsigned short Bt[128 * 132];
  __shared__ float zb[128];
  __shared__ float km[128];
  const int t = threadIdx.x, lane = t & 63, wave = t >> 6;
  const int wr = wave >> 1, wc = wave & 1;
  const int l4 = lane & 15, lg = lane >> 4;
  const int pb = xswz(blockIdx.x, 72) << 7, b = blockIdx.y;
  const float kSCf = (float)(0.08838834764831843 / 9216.0);

  const unsigned short* qs = qkvo + (size_t)b * BSTRIDE_QKV;     // q' section
  const unsigned short* lpb = lp + (size_t)b * BSTRIDE_C;        // lepe bf16
  float* ob = outp + (size_t)b * BSTRIDE_C;                      // final out f32

  if (t < 128) km[t] = ksum[(b << 7) + t];

  // ---- Phase 0: stage xh tile transposed -> Bt[px][ic] (bf16) ----
  {
    const unsigned short* B = xh + (size_t)b * BSTRIDE_C;
    #pragma unroll
    for (int i = 0; i < 8; ++i) {
      int id = t + (i << 8);
      int kp = id >> 5, pg = id & 31;
      const unsigned short* r0 = B + (size_t)(2 * kp) * HW + pb + (pg << 2);
      u16x4 a = *(const u16x4*)r0;
      u16x4 c = *(const u16x4*)(r0 + HW);
      #pragma unroll
      for (int j = 0; j < 4; ++j)
        *(unsigned*)&Bt[((pg << 2) + j) * 132 + 2 * kp] =
            (unsigned)a[j] | ((unsigned)c[j] << 16);
    }
  }
  __syncthreads();   // covers km write too

  // o-GEMM: A = x frags (px rows), B = w_o frags (d rows, k-contig)
  f32x4 acco[4][4];
  #pragma unroll
  for (int mp = 0; mp < 4; ++mp)
    #pragma unroll
    for (int nd = 0; nd < 4; ++nd) acco[mp][nd] = (f32x4){0.f, 0.f, 0.f, 0.f};

  #pragma unroll
  for (int ks = 0; ks < 4; ++ks) {
    short8v ax[4];
    #pragma unroll
    for (int mp = 0; mp < 4; ++mp) {
      int base = (wr * 64 + mp * 16 + l4) * 132 + ks * 32 + lg * 8;
      short4v lo = *(const short4v*)&Bt[base];
      short4v hi = *(const short4v*)&Bt[base + 4];
      short8v v;
      v[0] = lo[0]; v[1] = lo[1]; v[2] = lo[2]; v[3] = lo[3];
      v[4] = hi[0]; v[5] = hi[1]; v[6] = hi[2]; v[7] = hi[3];
      ax[mp] = v;
    }
    short8v pw[4];
    #pragma unroll
    for (int nd = 0; nd < 4; ++nd)
      pw[nd] = *(const short8v*)(woh + (size_t)(wc * 64 + nd * 16 + l4) * 128 + ks * 32 + lg * 8);
    #pragma unroll
    for (int nd = 0; nd < 4; ++nd)
      #pragma unroll
      for (int mp = 0; mp < 4; ++mp)
        acco[mp][nd] = __builtin_amdgcn_mfma_f32_16x16x32_bf16(ax[mp], pw[nd], acco[mp][nd], 0, 0, 0);
  }

  __syncthreads();   // all Bt (x) reads done

  // ---- Phase 1: stage q' -> Bt ----
  #pragma unroll
  for (int i = 0; i < 8; ++i) {
    int id = t + (i << 8);
    int kp = id >> 5, pg = id & 31;
    const unsigned short* r0 = qs + (size_t)(2 * kp) * HW + pb + (pg << 2);
    u16x4 a = *(const u16x4*)r0;
    u16x4 c = *(const u16x4*)(r0 + HW);
    #pragma unroll
    for (int j = 0; j < 4; ++j)
      *(unsigned*)&Bt[((pg << 2) + j) * 132 + 2 * kp] =
          (unsigned)a[j] | ((unsigned)c[j] << 16);
  }

  f32x4 acc[4][4];
  #pragma unroll
  for (int mp = 0; mp < 4; ++mp)
    #pragma unroll
    for (int nd = 0; nd < 4; ++nd) acc[mp][nd] = (f32x4){0.f, 0.f, 0.f, 0.f};

  __syncthreads();

  // MFMA1 with fused parallel z-partials
  const unsigned short* Ab = kvT + (size_t)b * 16384;
  float zp4[4] = {0.f, 0.f, 0.f, 0.f};
  #pragma unroll
  for (int ks = 0; ks < 4; ++ks) {
    f32x4 km0 = *(const f32x4*)&km[ks * 32 + lg * 8];
    f32x4 km1 = *(const f32x4*)&km[ks * 32 + lg * 8 + 4];
    short8v aq[4];
    #pragma unroll
    for (int mp = 0; mp < 4; ++mp) {
      int base = (wr * 64 + mp * 16 + l4) * 132 + ks * 32 + lg * 8;
      short4v lo = *(const short4v*)&Bt[base];
      short4v hi = *(const short4v*)&Bt[base + 4];
      short8v v;
      v[0] = lo[0]; v[1] = lo[1]; v[2] = lo[2]; v[3] = lo[3];
      v[4] = hi[0]; v[5] = hi[1]; v[6] = hi[2]; v[7] = hi[3];
      aq[mp] = v;
      #pragma unroll
      for (int e = 0; e < 4; ++e)
        zp4[mp] += b2f((unsigned short)v[e]) * km0[e]
                 + b2f((unsigned short)v[e + 4]) * km1[e];
    }
    short8v bkv[4];
    #pragma unroll
    for (int nd = 0; nd < 4; ++nd)
      bkv[nd] = *(const short8v*)(Ab + (size_t)(wc * 64 + nd * 16 + l4) * 128 + ks * 32 + lg * 8);
    #pragma unroll
    for (int nd = 0; nd < 4; ++nd)
      #pragma unroll
      for (int mp = 0; mp < 4; ++mp)
        acc[mp][nd] = __builtin_amdgcn_mfma_f32_16x16x32_bf16(aq[mp], bkv[nd], acc[mp][nd], 0, 0, 0);
  }

  // reduce z over lg (lane bits 4,5); px = wr*64+mp*16+l4
  #pragma unroll
  for (int mp = 0; mp < 4; ++mp) {
    zp4[mp] += __shfl_xor(zp4[mp], 16, 64);
    zp4[mp] += __shfl_xor(zp4[mp], 32, 64);
  }
  if (wc == 0 && lg == 0) {
    #pragma unroll
    for (int mp = 0; mp < 4; ++mp) zb[wr * 64 + mp * 16 + l4] = zp4[mp];
  }

  __syncthreads();   // Bt reads done; zb visible

  // ---- Phase 2: epilogue T -> Tt (reuse Bt) ----
  float bo[4];
  #pragma unroll
  for (int nd = 0; nd < 4; ++nd) bo[nd] = b_o[wc * 64 + nd * 16 + l4];

  #pragma unroll
  for (int mp = 0; mp < 4; ++mp) {
    int pxl = wr * 64 + mp * 16 + lg * 4;
    int px = pb + pxl;
    f32x4 zv = *(const f32x4*)&zb[pxl];
    f32x4 vm = *(const f32x4*)&vmean[(size_t)b * HW + px];
    f32x4 zfv, zvmv;
    #pragma unroll
    for (int i = 0; i < 4; ++i) {
      float z = zv[i] * kSCf;
      zfv[i]  = kSCf * (1.f + 1.f / (z + 1e-6f));
      zvmv[i] = z * vm[i];
    }
    #pragma unroll
    for (int nd = 0; nd < 4; ++nd) {
      int d = wc * 64 + nd * 16 + l4;
      u16x4 lev = *(const u16x4*)&lpb[(size_t)d * HW + px];
      #pragma unroll
      for (int i = 0; i < 4; ++i) {
        float ov = acco[mp][nd][i] + bo[nd];
        float r = (acc[mp][nd][i] * zfv[i] - zvmv[i] + b2f(lev[i])) * ov;
        Bt[(pxl + i) * 132 + d] = f2b(r);
      }
    }
  }

  __syncthreads();   // Tt complete

  // ---- Phase 3: MFMA2 out = T @ w_proj^T ----
  f32x4 acc2[4][4];
  #pragma unroll
  for (int mp = 0; mp < 4; ++mp)
    #pragma unroll
    for (int nd = 0; nd < 4; ++nd) acc2[mp][nd] = (f32x4){0.f, 0.f, 0.f, 0.f};

  #pragma unroll
  for (int ks = 0; ks < 4; ++ks) {
    short8v aq[4];
    #pragma unroll
    for (int mp = 0; mp < 4; ++mp) {
      int base = (wr * 64 + mp * 16 + l4) * 132 + ks * 32 + lg * 8;
      short4v lo = *(const short4v*)&Bt[base];
      short4v hi = *(const short4v*)&Bt[base + 4];
      short8v v;
      v[0] = lo[0]; v[1] = lo[1]; v[2] = lo[2]; v[3] = lo[3];
      v[4] = hi[0]; v[5] = hi[1]; v[6] = hi[2]; v[7] = hi[3];
      aq[mp] = v;
    }
    short8v pw[4];
    #pragma unroll
    for (int nd = 0; nd < 4; ++nd)
      pw[nd] = *(const short8v*)(wph + (size_t)(wc * 64 + nd * 16 + l4) * 128 + ks * 32 + lg * 8);
    #pragma unroll
    for (int nd = 0; nd < 4; ++nd)
      #pragma unroll
      for (int mp = 0; mp < 4; ++mp)
        acc2[mp][nd] = __builtin_amdgcn_mfma_f32_16x16x32_bf16(aq[mp], pw[nd], acc2[mp][nd], 0, 0, 0);
  }

  float bb[4];
  #pragma unroll
  for (int nd = 0; nd < 4; ++nd) bb[nd] = b_proj[wc * 64 + nd * 16 + l4];

  #pragma unroll
  for (int mp = 0; mp < 4; ++mp) {
    int px = pb + wr * 64 + mp * 16 + lg * 4;
    #pragma unroll
    for (int nd = 0; nd < 4; ++nd) {
      int oc = wc * 64 + nd * 16 + l4;
      f32x4 v;
      #pragma unroll
      for (int i = 0; i < 4; ++i) v[i] = acc2[mp][nd][i] + bb[nd];
      __builtin_nontemporal_store(v, (f32x4*)&ob[(size_t)oc * HW + px]);
    }
  }
}

extern "C" void kernel_launch(void* const* d_in, const int* in_sizes, int n_in,
                              void* d_out, int out_size, void* d_ws, size_t ws_size,
                              hipStream_t stream) {
  const float* x      = (const float*)d_in[0];
  const float* w_qkvo = (const float*)d_in[3];
  const float* b_qkvo = (const float*)d_in[4];
  const float* w_lepe = (const float*)d_in[5];
  const float* b_lepe = (const float*)d_in[6];
  const float* w_proj = (const float*)d_in[7];
  const float* b_proj = (const float*)d_in[8];
  const float* w_q = (const float*)d_in[9];
  const float* b_q = (const float*)d_in[10];
  const float* w_k = (const float*)d_in[11];
  const float* b_k = (const float*)d_in[12];
  const float* w_v = (const float*)d_in[13];
  const float* b_v = (const float*)d_in[14];
  float* out = (float*)d_out;

  // global: bf16 weights + bf16 copy of x
  unsigned short* wqh = (unsigned short*)d_ws;   // 65536 elems
  unsigned short* wph = wqh + 65536;             // 16384 elems -> 163840 bytes
  unsigned short* xh  = wph + 16384;             // 16*BSTRIDE_C elems = 37,748,736 B
  const size_t fixed_bytes = 163840 + (size_t)16 * BSTRIDE_C * 2;
  // per-batch (bytes): qkv bf16 7,077,888 ; kvpart f32 1,572,864 ; kvT bf16 32,768 ;
  //                    ksum f32 512 ; vmean f32 36,864 ; lepe bf16 2,359,296
  const size_t perb_bytes = 7077888 + 1572864 + 32768 + 512 + 36864 + 2359296;
  int G = 0;
  for (int g = 16; g >= 1; g >>= 1)
    if (fixed_bytes + (size_t)g * perb_bytes <= ws_size) { G = g; break; }
  if (G == 0) return;

  size_t off = fixed_bytes;
  unsigned short* qkv_h = (unsigned short*)((char*)d_ws + off);  off += (size_t)G * 7077888;
  float* kvpart = (float*)((char*)d_ws + off);                   off += (size_t)G * 1572864;
  unsigned short* kvT = (unsigned short*)((char*)d_ws + off);    off += (size_t)G * 32768;
  float* ksum = (float*)((char*)d_ws + off);                     off += (size_t)G * 512;
  float* vmeanp = (float*)((char*)d_ws + off);                   off += (size_t)G * 36864;
  unsigned short* lepe_h = (unsigned short*)((char*)d_ws + off);

  cvt_kernel<<<dim3(256), 256, 0, stream>>>(w_qkvo, wqh, 65536);
  cvt_kernel<<<dim3(64),  256, 0, stream>>>(w_proj, wph, 16384);
  // x -> bf16 once (both consumers previously rounded identically in staging)
  cvt8_kernel<<<dim3(9216), 256, 0, stream>>>(x, xh, 2359296);

  for (int b0 = 0; b0 < 16; b0 += G) {
    const unsigned short* xch = xh + (size_t)b0 * BSTRIDE_C;
    float* oc_ = out + (size_t)b0 * BSTRIDE_C;

    // qkv = 1x1 conv (bf16 in/out, channel-major); 3 oc-blocks (q,k,v) per px-tile
    gemm_k128s<0, 0, 3><<<dim3(72, G), 256, 0, stream>>>(
        wqh, xch, b_qkvo, qkv_h, BSTRIDE_C, BSTRIDE_QKV);
    // depthwise 3x3 q,k,v (in place, elu+1 on q,k), 5x5 lepe (bf16) -> ws, ksum
    dwconv_kernel<<<dim3(128, G), 256, 0, stream>>>(qkv_h, w_q, b_q, w_k, b_k, w_v, b_v,
                                                    w_lepe, b_lepe, lepe_h, ksum);
    // kv partials (+fused vmean) + reduce (-> kvT bf16)
    kv_mfma<<<dim3(KVS, G), 256, 0, stream>>>(qkv_h, kvpart, vmeanp);
    kvreduce<<<dim3(8, G), 256, 0, stream>>>(kvpart, kvT);
    // fused o-GEMM + attention epilogue + projection -> d_out slice (f32, nt)
    attn_proj<<<dim3(72, G), 256, 0, stream>>>(qkv_h, xch, kvT, ksum, vmeanp, lepe_h,
                                               wqh + (size_t)384 * 128, b_qkvo + 384,
                                               wph, b_proj, oc_);
  }
}

// Round 11
// 261.528 us; speedup vs baseline: 1.2586x; 1.0640x over previous
//
#include <hip/hip_runtime.h>
#include <math.h>

// B=16, C=128, H=W=96, HW=9216
#define HW 9216
#define BSTRIDE_QKV  ((size_t)3538944)   // 384*9216 (elements) - q,k,v only
#define BSTRIDE_C    ((size_t)1179648)   // 128*9216 (elements)
#define KVS 24                           // kv partial splits (384 px each)

typedef __attribute__((ext_vector_type(4))) short short4v;
typedef __attribute__((ext_vector_type(8))) short short8v;
typedef __attribute__((ext_vector_type(4))) float f32x4;
typedef __attribute__((ext_vector_type(4))) unsigned short u16x4;

__device__ __forceinline__ unsigned short f2b(float f) {
  union { float f; unsigned u; } v; v.f = f;
  unsigned r = (v.u + 0x7fffu + ((v.u >> 16) & 1u)) >> 16;
  return (unsigned short)r;
}
__device__ __forceinline__ float b2f(unsigned short h) {
  union { unsigned u; float f; } v; v.u = ((unsigned)h) << 16;
  return v.f;
}
// XCD-aware swizzle (nx multiple of 8)
__device__ __forceinline__ int xswz(int x, int nx) {
  return (x & 7) * (nx >> 3) + (x >> 3);
}

// ---------------- f32 -> bf16 weight conversion ----------------
__global__ void cvt_kernel(const float* __restrict__ in, unsigned short* __restrict__ out, int n) {
  int i = blockIdx.x * 256 + threadIdx.x;
  if (i < n) out[i] = f2b(in[i]);
}

// ---------------- GEMM, K=128, 64-px tiles, swapped-operand.
// D[px][oc] per lane = 4 consecutive px. A-frags = activation from LDS Bt[px][k].
// B-frags = weights [oc][128] k-contig (L2-hot). Grid (144, B).
template<int BSRC_F32, int NOCB>
__global__ __launch_bounds__(256) void gemm_k128s(
    const unsigned short* __restrict__ A, const void* __restrict__ Bv,
    const float* __restrict__ bias, unsigned short* __restrict__ Ov,
    size_t bstrB, size_t bstrO)
{
  __shared__ unsigned short Bt[64 * 132];
  const int t = threadIdx.x, lane = t & 63, wave = t >> 6;
  const int wr = wave >> 1, wc = wave & 1;
  const int l4 = lane & 15, lg = lane >> 4;
  const int pb = xswz(blockIdx.x, 144) << 6, b = blockIdx.y;

  if (BSRC_F32) {
    const float* B = (const float*)Bv + (size_t)b * bstrB;
    #pragma unroll
    for (int i = 0; i < 4; ++i) {
      int id = t + (i << 8);
      int kp = id >> 4, pg = id & 15;
      const float* r0 = B + (size_t)(2 * kp) * HW + pb + (pg << 2);
      f32x4 a = *(const f32x4*)r0;
      f32x4 c = *(const f32x4*)(r0 + HW);
      #pragma unroll
      for (int j = 0; j < 4; ++j)
        *(unsigned*)&Bt[((pg << 2) + j) * 132 + 2 * kp] =
            (unsigned)f2b(a[j]) | ((unsigned)f2b(c[j]) << 16);
    }
  } else {
    const unsigned short* B = (const unsigned short*)Bv + (size_t)b * bstrB;
    #pragma unroll
    for (int i = 0; i < 4; ++i) {
      int id = t + (i << 8);
      int kp = id >> 4, pg = id & 15;
      const unsigned short* r0 = B + (size_t)(2 * kp) * HW + pb + (pg << 2);
      u16x4 a = *(const u16x4*)r0;
      u16x4 c = *(const u16x4*)(r0 + HW);
      #pragma unroll
      for (int j = 0; j < 4; ++j)
        *(unsigned*)&Bt[((pg << 2) + j) * 132 + 2 * kp] =
            (unsigned)a[j] | ((unsigned)c[j] << 16);
    }
  }

  __syncthreads();

  // A-frags: 32 px per wr-half, 2 mp sub-blocks
  short8v af[2][4];
  #pragma unroll
  for (int mp = 0; mp < 2; ++mp)
    #pragma unroll
    for (int ks = 0; ks < 4; ++ks) {
      int base = (wr * 32 + mp * 16 + l4) * 132 + ks * 32 + lg * 8;
      short4v lo = *(const short4v*)&Bt[base];
      short4v hi = *(const short4v*)&Bt[base + 4];
      short8v v;
      v[0] = lo[0]; v[1] = lo[1]; v[2] = lo[2]; v[3] = lo[3];
      v[4] = hi[0]; v[5] = hi[1]; v[6] = hi[2]; v[7] = hi[3];
      af[mp][ks] = v;
    }

  for (int co = 0; co < NOCB; ++co) {
    f32x4 acc[2][4];
    #pragma unroll
    for (int mp = 0; mp < 2; ++mp)
      #pragma unroll
      for (int nd = 0; nd < 4; ++nd) acc[mp][nd] = (f32x4){0.f, 0.f, 0.f, 0.f};

    #pragma unroll
    for (int ks = 0; ks < 4; ++ks) {
      short8v bfk[4];
      #pragma unroll
      for (int nd = 0; nd < 4; ++nd)
        bfk[nd] = *(const short8v*)(A + (size_t)(co * 128 + wc * 64 + nd * 16 + l4) * 128 + ks * 32 + lg * 8);
      #pragma unroll
      for (int nd = 0; nd < 4; ++nd)
        #pragma unroll
        for (int mp = 0; mp < 2; ++mp)
          acc[mp][nd] = __builtin_amdgcn_mfma_f32_16x16x32_bf16(af[mp][ks], bfk[nd], acc[mp][nd], 0, 0, 0);
    }

    float bb[4];
    #pragma unroll
    for (int nd = 0; nd < 4; ++nd) bb[nd] = bias[co * 128 + wc * 64 + nd * 16 + l4];

    unsigned short* O = Ov + (size_t)b * bstrO;
    #pragma unroll
    for (int mp = 0; mp < 2; ++mp) {
      int px = pb + wr * 32 + mp * 16 + lg * 4;
      #pragma unroll
      for (int nd = 0; nd < 4; ++nd) {
        int oc = co * 128 + wc * 64 + nd * 16 + l4;
        u16x4 v;
        #pragma unroll
        for (int i = 0; i < 4; ++i) v[i] = f2b(acc[mp][nd][i] + bb[nd]);
        *(u16x4*)&O[(size_t)oc * HW + px] = v;
      }
    }
  }
}

// ---------------- depthwise convs, strip-vectorized ----------------
__device__ __forceinline__ void stage_plane(const unsigned short* __restrict__ g,
                                            float* __restrict__ sp, int t) {
  #pragma unroll
  for (int i = 0; i < 9; ++i) {
    int f = (t + (i << 8)) << 2;
    u16x4 u = *(const u16x4*)&g[f];
    f32x4 fv;
    fv[0] = b2f(u[0]); fv[1] = b2f(u[1]); fv[2] = b2f(u[2]); fv[3] = b2f(u[3]);
    *(f32x4*)&sp[f] = fv;
  }
}

__device__ __forceinline__ f32x4 conv3_strip(const float* __restrict__ sp, int base,
                                             const float* __restrict__ w9,
                                             bool j0, bool j23, f32x4* cen) {
  f32x4 acc = (f32x4){0.f, 0.f, 0.f, 0.f};
  #pragma unroll
  for (int ky = 0; ky < 3; ++ky) {
    const float* rowp = sp + base + (ky - 1) * 96;
    f32x4 w0 = *(const f32x4*)(rowp - 4);
    f32x4 w1 = *(const f32x4*)(rowp);
    f32x4 w2 = *(const f32x4*)(rowp + 4);
    float xm1 = j0 ? 0.f : w0[3];
    float xp4 = j23 ? 0.f : w2[0];
    float k0 = w9[ky * 3], k1 = w9[ky * 3 + 1], k2 = w9[ky * 3 + 2];
    acc[0] += k0 * xm1   + k1 * w1[0] + k2 * w1[1];
    acc[1] += k0 * w1[0] + k1 * w1[1] + k2 * w1[2];
    acc[2] += k0 * w1[1] + k1 * w1[2] + k2 * w1[3];
    acc[3] += k0 * w1[2] + k1 * w1[3] + k2 * xp4;
    if (ky == 1) *cen = w1;
  }
  return acc;
}

__global__ __launch_bounds__(256) void dwconv_kernel(
    unsigned short* __restrict__ qkvo,
    const float* __restrict__ w_q, const float* __restrict__ b_q,
    const float* __restrict__ w_k, const float* __restrict__ b_k,
    const float* __restrict__ w_v, const float* __restrict__ b_v,
    const float* __restrict__ w_lepe, const float* __restrict__ b_lepe,
    unsigned short* __restrict__ lp, float* __restrict__ ksum)
{
  __shared__ float sb[9612];
  __shared__ float red[256];
  const int c = blockIdx.x, b = blockIdx.y, t = threadIdx.x;
  unsigned short* qg = qkvo + ((size_t)b * 384 + c) * HW;
  unsigned short* kg = qg + (size_t)128 * HW;
  unsigned short* vg = qg + (size_t)256 * HW;
  unsigned short* lg = lp + ((size_t)b * 128 + c) * HW;
  float* sp = sb + 196;

  for (int i = t; i < 384; i += 256) {
    int idx = (i < 192) ? (i - 192) : (9024 + i);
    sp[idx] = 0.f;
  }

  // ---- Q ----
  {
    stage_plane(qg, sp, t);
    float w9[9];
    #pragma unroll
    for (int i = 0; i < 9; ++i) w9[i] = w_q[c * 9 + i];
    float bb = b_q[c];
    __syncthreads();
    for (int i = 0; i < 9; ++i) {
      int s = t + (i << 8);
      int r = s / 24, j = s - r * 24;
      int base = r * 96 + (j << 2);
      f32x4 cen;
      f32x4 a = conv3_strip(sp, base, w9, j == 0, j == 23, &cen);
      u16x4 o;
      #pragma unroll
      for (int k = 0; k < 4; ++k) {
        float v = cen[k] + bb + a[k];
        o[k] = f2b(v > 0.f ? v + 1.f : __expf(v));
      }
      *(u16x4*)&qg[base] = o;
    }
    __syncthreads();
  }
  // ---- K ----
  float kacc = 0.f;
  {
    stage_plane(kg, sp, t);
    float w9[9];
    #pragma unroll
    for (int i = 0; i < 9; ++i) w9[i] = w_k[c * 9 + i];
    float bb = b_k[c];
    __syncthreads();
    for (int i = 0; i < 9; ++i) {
      int s = t + (i << 8);
      int r = s / 24, j = s - r * 24;
      int base = r * 96 + (j << 2);
      f32x4 cen;
      f32x4 a = conv3_strip(sp, base, w9, j == 0, j == 23, &cen);
      u16x4 o;
      #pragma unroll
      for (int k = 0; k < 4; ++k) {
        float v = cen[k] + bb + a[k];
        float e = v > 0.f ? v + 1.f : __expf(v);
        o[k] = f2b(e);
        kacc += e;
      }
      *(u16x4*)&kg[base] = o;
    }
    __syncthreads();
  }
  // ---- V + lepe (lepe stored bf16) ----
  {
    stage_plane(vg, sp, t);
    float w9[9], w25[25];
    #pragma unroll
    for (int i = 0; i < 9; ++i) w9[i] = w_v[c * 9 + i];
    #pragma unroll
    for (int i = 0; i < 25; ++i) w25[i] = w_lepe[c * 25 + i];
    float bv = b_v[c], bl = b_lepe[c];
    __syncthreads();
    for (int i = 0; i < 9; ++i) {
      int s = t + (i << 8);
      int r = s / 24, j = s - r * 24;
      int base = r * 96 + (j << 2);
      bool j0 = (j == 0), j23 = (j == 23);
      f32x4 a3 = (f32x4){0.f, 0.f, 0.f, 0.f};
      f32x4 a5 = (f32x4){0.f, 0.f, 0.f, 0.f};
      f32x4 cen = (f32x4){0.f, 0.f, 0.f, 0.f};
      #pragma unroll
      for (int ky = 0; ky < 5; ++ky) {
        const float* rowp = sp + base + (ky - 2) * 96;
        f32x4 w0 = *(const f32x4*)(rowp - 4);
        f32x4 w1 = *(const f32x4*)(rowp);
        f32x4 w2 = *(const f32x4*)(rowp + 4);
        float xm2 = j0 ? 0.f : w0[2];
        float xm1 = j0 ? 0.f : w0[3];
        float xp4 = j23 ? 0.f : w2[0];
        float xp5 = j23 ? 0.f : w2[1];
        const float* wr5 = w25 + ky * 5;
        a5[0] += wr5[0]*xm2   + wr5[1]*xm1   + wr5[2]*w1[0] + wr5[3]*w1[1] + wr5[4]*w1[2];
        a5[1] += wr5[0]*xm1   + wr5[1]*w1[0] + wr5[2]*w1[1] + wr5[3]*w1[2] + wr5[4]*w1[3];
        a5[2] += wr5[0]*w1[0] + wr5[1]*w1[1] + wr5[2]*w1[2] + wr5[3]*w1[3] + wr5[4]*xp4;
        a5[3] += wr5[0]*w1[1] + wr5[1]*w1[2] + wr5[2]*w1[3] + wr5[3]*xp4   + wr5[4]*xp5;
        if (ky >= 1 && ky <= 3) {
          float k0 = w9[(ky-1)*3], k1 = w9[(ky-1)*3+1], k2 = w9[(ky-1)*3+2];
          a3[0] += k0 * xm1   + k1 * w1[0] + k2 * w1[1];
          a3[1] += k0 * w1[0] + k1 * w1[1] + k2 * w1[2];
          a3[2] += k0 * w1[1] + k1 * w1[2] + k2 * w1[3];
          a3[3] += k0 * w1[2] + k1 * w1[3] + k2 * xp4;
          if (ky == 2) cen = w1;
        }
      }
      u16x4 o, lo16;
      #pragma unroll
      for (int k = 0; k < 4; ++k) {
        o[k] = f2b(cen[k] + bv + a3[k]);
        lo16[k] = f2b(bl + a5[k]);
      }
      *(u16x4*)&vg[base] = o;
      *(u16x4*)&lg[base] = lo16;
    }
  }
  red[t] = kacc; __syncthreads();
  for (int s2 = 128; s2 > 0; s2 >>= 1) { if (t < s2) red[t] += red[t + s2]; __syncthreads(); }
  if (t == 0) ksum[b * 128 + c] = red[0];
}

// ---------------- kv partials over 384-px splits + fused vmean ----------------
__global__ __launch_bounds__(256) void kv_mfma(
    const unsigned short* __restrict__ qkvo, float* __restrict__ part,
    float* __restrict__ vmean)
{
  __shared__ float vml[2][384];
  const int t = threadIdx.x, lane = t & 63, wave = t >> 6;
  const int wr = wave >> 1, wc = wave & 1;
  const int l4 = lane & 15, lg = lane >> 4;
  const int s = xswz(blockIdx.x, KVS), b = blockIdx.y;
  const unsigned short* kbase = qkvo + (size_t)b * BSTRIDE_QKV + (size_t)128 * HW;
  const unsigned short* vbase = kbase + (size_t)128 * HW;
  const int p0 = s * 384;

  f32x4 acc[4][4];
  #pragma unroll
  for (int m = 0; m < 4; ++m)
    #pragma unroll
    for (int n = 0; n < 4; ++n) acc[m][n] = (f32x4){0.f, 0.f, 0.f, 0.f};

  for (int kk = 0; kk < 12; ++kk) {
    int p = p0 + kk * 32 + lg * 8;
    short8v ka[4], va[4];
    #pragma unroll
    for (int m = 0; m < 4; ++m) ka[m] = *(const short8v*)(kbase + (size_t)(wr * 64 + m * 16 + l4) * HW + p);
    #pragma unroll
    for (int n = 0; n < 4; ++n) va[n] = *(const short8v*)(vbase + (size_t)(wc * 64 + n * 16 + l4) * HW + p);

    if (wr == 0) {
      float pv[8];
      #pragma unroll
      for (int e = 0; e < 8; ++e) {
        pv[e] = b2f((unsigned short)va[0][e]) + b2f((unsigned short)va[1][e])
              + b2f((unsigned short)va[2][e]) + b2f((unsigned short)va[3][e]);
        #pragma unroll
        for (int m2 = 1; m2 < 16; m2 <<= 1)
          pv[e] += __shfl_xor(pv[e], m2, 64);
      }
      if (l4 == 0) {
        #pragma unroll
        for (int e = 0; e < 8; ++e) vml[wc][kk * 32 + lg * 8 + e] = pv[e];
      }
    }

    #pragma unroll
    for (int n = 0; n < 4; ++n)
      #pragma unroll
      for (int m = 0; m < 4; ++m)
        acc[m][n] = __builtin_amdgcn_mfma_f32_16x16x32_bf16(ka[m], va[n], acc[m][n], 0, 0, 0);
  }

  float* pp = part + ((size_t)b * KVS + s) * 16384;
  #pragma unroll
  for (int m = 0; m < 4; ++m)
    #pragma unroll
    for (int n = 0; n < 4; ++n) {
      int d = wc * 64 + n * 16 + l4;
      #pragma unroll
      for (int i = 0; i < 4; ++i) {
        int cch = wr * 64 + m * 16 + lg * 4 + i;
        pp[(cch << 7) + d] = acc[m][n][i];
      }
    }

  __syncthreads();
  for (int i = t; i < 384; i += 256)
    vmean[(size_t)b * HW + p0 + i] = (vml[0][i] + vml[1][i]) * (1.f / 128.f);
}

// ---------------- reduce partials over KVS splits -> kvT[d][c] bf16 ----------------
__global__ void kvreduce(const float* __restrict__ part, unsigned short* __restrict__ kvT) {
  const int b = blockIdx.y;
  const int e0 = blockIdx.x * 2048 + threadIdx.x;
  const float* pb_ = part + (size_t)b * KVS * 16384;
  for (int i = 0; i < 8; ++i) {
    int e = e0 + i * 256;
    int cch = e >> 7, d = e & 127;
    float sum = 0.f;
    #pragma unroll 8
    for (int s = 0; s < KVS; ++s) sum += pb_[(size_t)s * 16384 + e];
    kvT[(size_t)b * 16384 + d * 128 + cch] = f2b(sum);
  }
}

// ---------------- fused o-GEMM + attention + projection, 64-px tiles ----------------
// Phase 0: stage x-tile (f32->bf16) -> Bt, MFMA_o: o[px][d] (held in regs).
// Phase 1: stage q' -> Bt, MFMA1: acc = q' @ kvT with fused parallel z-partials.
// Phase 2: epilogue T = (acc*zf - z*vmean + lepe)*(o+b_o) -> Tt (LDS).
// Phase 3: MFMA2: out = T @ w_proj^T + b_proj, nontemporal f32x4 stores. Grid (144,B).
__global__ __launch_bounds__(256) void attn_proj(
    const unsigned short* __restrict__ qkvo, const float* __restrict__ xin,
    const unsigned short* __restrict__ kvT,
    const float* __restrict__ ksum, const float* __restrict__ vmean,
    const unsigned short* __restrict__ lp,
    const unsigned short* __restrict__ woh, const float* __restrict__ b_o,
    const unsigned short* __restrict__ wph, const float* __restrict__ b_proj,
    float* __restrict__ outp)
{
  __shared__ unsigned short Bt[64 * 132];
  __shared__ float zb[64];
  __shared__ float km[128];
  const int t = threadIdx.x, lane = t & 63, wave = t >> 6;
  const int wr = wave >> 1, wc = wave & 1;
  const int l4 = lane & 15, lg = lane >> 4;
  const int pb = xswz(blockIdx.x, 144) << 6, b = blockIdx.y;
  const float kSCf = (float)(0.08838834764831843 / 9216.0);

  const unsigned short* qs = qkvo + (size_t)b * BSTRIDE_QKV;     // q' section
  const unsigned short* lpb = lp + (size_t)b * BSTRIDE_C;        // lepe bf16
  float* ob = outp + (size_t)b * BSTRIDE_C;                      // final out f32

  if (t < 128) km[t] = ksum[(b << 7) + t];

  // ---- Phase 0: stage x tile transposed -> Bt[px][ic] (bf16) ----
  {
    const float* B = xin + (size_t)b * BSTRIDE_C;
    #pragma unroll
    for (int i = 0; i < 4; ++i) {
      int id = t + (i << 8);
      int kp = id >> 4, pg = id & 15;
      const float* r0 = B + (size_t)(2 * kp) * HW + pb + (pg << 2);
      f32x4 a = *(const f32x4*)r0;
      f32x4 c = *(const f32x4*)(r0 + HW);
      #pragma unroll
      for (int j = 0; j < 4; ++j)
        *(unsigned*)&Bt[((pg << 2) + j) * 132 + 2 * kp] =
            (unsigned)f2b(a[j]) | ((unsigned)f2b(c[j]) << 16);
    }
  }
  __syncthreads();   // covers km write too

  // o-GEMM: A = x frags (px rows), B = w_o frags (d rows, k-contig)
  f32x4 acco[2][4];
  #pragma unroll
  for (int mp = 0; mp < 2; ++mp)
    #pragma unroll
    for (int nd = 0; nd < 4; ++nd) acco[mp][nd] = (f32x4){0.f, 0.f, 0.f, 0.f};

  #pragma unroll
  for (int ks = 0; ks < 4; ++ks) {
    short8v ax[2];
    #pragma unroll
    for (int mp = 0; mp < 2; ++mp) {
      int base = (wr * 32 + mp * 16 + l4) * 132 + ks * 32 + lg * 8;
      short4v lo = *(const short4v*)&Bt[base];
      short4v hi = *(const short4v*)&Bt[base + 4];
      short8v v;
      v[0] = lo[0]; v[1] = lo[1]; v[2] = lo[2]; v[3] = lo[3];
      v[4] = hi[0]; v[5] = hi[1]; v[6] = hi[2]; v[7] = hi[3];
      ax[mp] = v;
    }
    short8v pw[4];
    #pragma unroll
    for (int nd = 0; nd < 4; ++nd)
      pw[nd] = *(const short8v*)(woh + (size_t)(wc * 64 + nd * 16 + l4) * 128 + ks * 32 + lg * 8);
    #pragma unroll
    for (int nd = 0; nd < 4; ++nd)
      #pragma unroll
      for (int mp = 0; mp < 2; ++mp)
        acco[mp][nd] = __builtin_amdgcn_mfma_f32_16x16x32_bf16(ax[mp], pw[nd], acco[mp][nd], 0, 0, 0);
  }

  __syncthreads();   // all Bt (x) reads done

  // ---- Phase 1: stage q' -> Bt ----
  #pragma unroll
  for (int i = 0; i < 4; ++i) {
    int id = t + (i << 8);
    int kp = id >> 4, pg = id & 15;
    const unsigned short* r0 = qs + (size_t)(2 * kp) * HW + pb + (pg << 2);
    u16x4 a = *(const u16x4*)r0;
    u16x4 c = *(const u16x4*)(r0 + HW);
    #pragma unroll
    for (int j = 0; j < 4; ++j)
      *(unsigned*)&Bt[((pg << 2) + j) * 132 + 2 * kp] =
          (unsigned)a[j] | ((unsigned)c[j] << 16);
  }

  f32x4 acc[2][4];
  #pragma unroll
  for (int mp = 0; mp < 2; ++mp)
    #pragma unroll
    for (int nd = 0; nd < 4; ++nd) acc[mp][nd] = (f32x4){0.f, 0.f, 0.f, 0.f};

  __syncthreads();

  // MFMA1 with fused parallel z-partials
  const unsigned short* Ab = kvT + (size_t)b * 16384;
  float zp[2] = {0.f, 0.f};
  #pragma unroll
  for (int ks = 0; ks < 4; ++ks) {
    f32x4 km0 = *(const f32x4*)&km[ks * 32 + lg * 8];
    f32x4 km1 = *(const f32x4*)&km[ks * 32 + lg * 8 + 4];
    short8v aq[2];
    #pragma unroll
    for (int mp = 0; mp < 2; ++mp) {
      int base = (wr * 32 + mp * 16 + l4) * 132 + ks * 32 + lg * 8;
      short4v lo = *(const short4v*)&Bt[base];
      short4v hi = *(const short4v*)&Bt[base + 4];
      short8v v;
      v[0] = lo[0]; v[1] = lo[1]; v[2] = lo[2]; v[3] = lo[3];
      v[4] = hi[0]; v[5] = hi[1]; v[6] = hi[2]; v[7] = hi[3];
      aq[mp] = v;
      #pragma unroll
      for (int e = 0; e < 4; ++e)
        zp[mp] += b2f((unsigned short)v[e]) * km0[e]
                + b2f((unsigned short)v[e + 4]) * km1[e];
    }
    short8v bkv[4];
    #pragma unroll
    for (int nd = 0; nd < 4; ++nd)
      bkv[nd] = *(const short8v*)(Ab + (size_t)(wc * 64 + nd * 16 + l4) * 128 + ks * 32 + lg * 8);
    #pragma unroll
    for (int nd = 0; nd < 4; ++nd)
      #pragma unroll
      for (int mp = 0; mp < 2; ++mp)
        acc[mp][nd] = __builtin_amdgcn_mfma_f32_16x16x32_bf16(aq[mp], bkv[nd], acc[mp][nd], 0, 0, 0);
  }

  // reduce z over lg (lane bits 4,5); px = wr*32+mp*16+l4
  #pragma unroll
  for (int mp = 0; mp < 2; ++mp) {
    zp[mp] += __shfl_xor(zp[mp], 16, 64);
    zp[mp] += __shfl_xor(zp[mp], 32, 64);
  }
  if (wc == 0 && lg == 0) {
    #pragma unroll
    for (int mp = 0; mp < 2; ++mp) zb[wr * 32 + mp * 16 + l4] = zp[mp];
  }

  __syncthreads();   // Bt reads done; zb visible

  // ---- Phase 2: epilogue T -> Tt (reuse Bt) ----
  float bo[4];
  #pragma unroll
  for (int nd = 0; nd < 4; ++nd) bo[nd] = b_o[wc * 64 + nd * 16 + l4];

  #pragma unroll
  for (int mp = 0; mp < 2; ++mp) {
    int pxl = wr * 32 + mp * 16 + lg * 4;
    int px = pb + pxl;
    f32x4 zv = *(const f32x4*)&zb[pxl];
    f32x4 vm = *(const f32x4*)&vmean[(size_t)b * HW + px];
    f32x4 zfv, zvmv;
    #pragma unroll
    for (int i = 0; i < 4; ++i) {
      float z = zv[i] * kSCf;
      zfv[i]  = kSCf * (1.f + 1.f / (z + 1e-6f));
      zvmv[i] = z * vm[i];
    }
    #pragma unroll
    for (int nd = 0; nd < 4; ++nd) {
      int d = wc * 64 + nd * 16 + l4;
      u16x4 lev = *(const u16x4*)&lpb[(size_t)d * HW + px];
      #pragma unroll
      for (int i = 0; i < 4; ++i) {
        float ov = acco[mp][nd][i] + bo[nd];
        float r = (acc[mp][nd][i] * zfv[i] - zvmv[i] + b2f(lev[i])) * ov;
        Bt[(pxl + i) * 132 + d] = f2b(r);
      }
    }
  }

  __syncthreads();   // Tt complete

  // ---- Phase 3: MFMA2 out = T @ w_proj^T ----
  f32x4 acc2[2][4];
  #pragma unroll
  for (int mp = 0; mp < 2; ++mp)
    #pragma unroll
    for (int nd = 0; nd < 4; ++nd) acc2[mp][nd] = (f32x4){0.f, 0.f, 0.f, 0.f};

  #pragma unroll
  for (int ks = 0; ks < 4; ++ks) {
    short8v aq[2];
    #pragma unroll
    for (int mp = 0; mp < 2; ++mp) {
      int base = (wr * 32 + mp * 16 + l4) * 132 + ks * 32 + lg * 8;
      short4v lo = *(const short4v*)&Bt[base];
      short4v hi = *(const short4v*)&Bt[base + 4];
      short8v v;
      v[0] = lo[0]; v[1] = lo[1]; v[2] = lo[2]; v[3] = lo[3];
      v[4] = hi[0]; v[5] = hi[1]; v[6] = hi[2]; v[7] = hi[3];
      aq[mp] = v;
    }
    short8v pw[4];
    #pragma unroll
    for (int nd = 0; nd < 4; ++nd)
      pw[nd] = *(const short8v*)(wph + (size_t)(wc * 64 + nd * 16 + l4) * 128 + ks * 32 + lg * 8);
    #pragma unroll
    for (int nd = 0; nd < 4; ++nd)
      #pragma unroll
      for (int mp = 0; mp < 2; ++mp)
        acc2[mp][nd] = __builtin_amdgcn_mfma_f32_16x16x32_bf16(aq[mp], pw[nd], acc2[mp][nd], 0, 0, 0);
  }

  float bb[4];
  #pragma unroll
  for (int nd = 0; nd < 4; ++nd) bb[nd] = b_proj[wc * 64 + nd * 16 + l4];

  #pragma unroll
  for (int mp = 0; mp < 2; ++mp) {
    int px = pb + wr * 32 + mp * 16 + lg * 4;
    #pragma unroll
    for (int nd = 0; nd < 4; ++nd) {
      int oc = wc * 64 + nd * 16 + l4;
      f32x4 v;
      #pragma unroll
      for (int i = 0; i < 4; ++i) v[i] = acc2[mp][nd][i] + bb[nd];
      __builtin_nontemporal_store(v, (f32x4*)&ob[(size_t)oc * HW + px]);
    }
  }
}

extern "C" void kernel_launch(void* const* d_in, const int* in_sizes, int n_in,
                              void* d_out, int out_size, void* d_ws, size_t ws_size,
                              hipStream_t stream) {
  const float* x      = (const float*)d_in[0];
  const float* w_qkvo = (const float*)d_in[3];
  const float* b_qkvo = (const float*)d_in[4];
  const float* w_lepe = (const float*)d_in[5];
  const float* b_lepe = (const float*)d_in[6];
  const float* w_proj = (const float*)d_in[7];
  const float* b_proj = (const float*)d_in[8];
  const float* w_q = (const float*)d_in[9];
  const float* b_q = (const float*)d_in[10];
  const float* w_k = (const float*)d_in[11];
  const float* b_k = (const float*)d_in[12];
  const float* w_v = (const float*)d_in[13];
  const float* b_v = (const float*)d_in[14];
  float* out = (float*)d_out;

  // global: bf16 weights (all 512 rows of w_qkvo; rows 384.. = w_o used in attn_proj)
  unsigned short* wqh = (unsigned short*)d_ws;   // 65536
  unsigned short* wph = wqh + 65536;             // 16384  -> 163840 bytes total
  // per-batch (bytes): qkv bf16 7,077,888 ; kvpart f32 1,572,864 ; kvT bf16 32,768 ;
  //                    ksum f32 512 ; vmean f32 36,864 ; lepe bf16 2,359,296
  const size_t perb_bytes = 7077888 + 1572864 + 32768 + 512 + 36864 + 2359296;
  int G = 0;
  for (int g = 16; g >= 1; g >>= 1)
    if ((size_t)163840 + (size_t)g * perb_bytes <= ws_size) { G = g; break; }
  if (G == 0) return;

  size_t off = 163840;
  unsigned short* qkv_h = (unsigned short*)((char*)d_ws + off);  off += (size_t)G * 7077888;
  float* kvpart = (float*)((char*)d_ws + off);                   off += (size_t)G * 1572864;
  unsigned short* kvT = (unsigned short*)((char*)d_ws + off);    off += (size_t)G * 32768;
  float* ksum = (float*)((char*)d_ws + off);                     off += (size_t)G * 512;
  float* vmeanp = (float*)((char*)d_ws + off);                   off += (size_t)G * 36864;
  unsigned short* lepe_h = (unsigned short*)((char*)d_ws + off);

  cvt_kernel<<<dim3(256), 256, 0, stream>>>(w_qkvo, wqh, 65536);
  cvt_kernel<<<dim3(64),  256, 0, stream>>>(w_proj, wph, 16384);

  for (int b0 = 0; b0 < 16; b0 += G) {
    const float* xc  = x   + (size_t)b0 * BSTRIDE_C;
    float*       oc_ = out + (size_t)b0 * BSTRIDE_C;

    // qkv = 1x1 conv (bf16 out, channel-major); 64-px tiles, 3 oc-blocks
    gemm_k128s<1, 3><<<dim3(144, G), 256, 0, stream>>>(
        wqh, xc, b_qkvo, qkv_h, BSTRIDE_C, BSTRIDE_QKV);
    // depthwise 3x3 q,k,v (in place, elu+1 on q,k), 5x5 lepe (bf16) -> ws, ksum
    dwconv_kernel<<<dim3(128, G), 256, 0, stream>>>(qkv_h, w_q, b_q, w_k, b_k, w_v, b_v,
                                                    w_lepe, b_lepe, lepe_h, ksum);
    // kv partials (+fused vmean) + reduce (-> kvT bf16)
    kv_mfma<<<dim3(KVS, G), 256, 0, stream>>>(qkv_h, kvpart, vmeanp);
    kvreduce<<<dim3(8, G), 256, 0, stream>>>(kvpart, kvT);
    // fused o-GEMM + attention epilogue + projection -> d_out slice (f32, nt)
    attn_proj<<<dim3(144, G), 256, 0, stream>>>(qkv_h, xc, kvT, ksum, vmeanp, lepe_h,
                                                wqh + (size_t)384 * 128, b_qkvo + 384,
                                                wph, b_proj, oc_);
  }
}